// Round 2
// baseline (270.945 us; speedup 1.0000x reference)
//
#include <hip/hip_runtime.h>
#include <hip/hip_bf16.h>
#include <stdint.h>
#include <math.h>

// ---------------------------------------------------------------------------
// JointAttention: dual-stream rmsnorm -> QKV proj -> RoPE -> joint attention
// over concat(a, x) (4096 tokens, 16 q-heads, 4 kv-heads tiled h%4) -> out proj.
// All matmuls in bf16 MFMA, fp32 accumulate.
//
// R10 = R9 with attn LDS staging removed (K/V are L2-resident: 4 MB total =
// one XCD L2; staging was pure overhead and its barrier phase-locked the
// 2 waves/SIMD into dependency stalls ~75% of the time):
//  - K frags loaded DIRECTLY from KB: lane (quad,l15) of wave (qsel,ksel)
//    reads key row g(2*ksel+jj, l15) = 32*ksel + 8*(l15>>2) + 4*jj + (l15&3)
//    at d-chunk quad*8 (+32) -- the exact frags the permuted-LDS path
//    produced, so the exp'd-S^T -> PV B-frag packing is unchanged.
//  - V^T frags loaded directly from VT[d][key] (16B contiguous per lane).
//  - Register double-buffer (2 tiles of frags in flight); loads for tile
//    kt+2 issued one full compute phase ahead -> covers L2 latency. NO
//    barrier in the main loop; waves free-run.
//  - Small LDS buffer (35 KB) only for the final ksel-pair combine
//    (1 barrier per kernel).
// ---------------------------------------------------------------------------

#define NSEQ 2048
#define NJ   4096
#define DIMM 1024

typedef __attribute__((ext_vector_type(4))) float f32x4;
typedef __attribute__((ext_vector_type(8))) short bf16x8;
typedef __attribute__((ext_vector_type(4))) short bf16x4;

__device__ __forceinline__ unsigned short f2bf(float f) {
  union { float f; uint32_t u; } v; v.f = f;
  return (unsigned short)((v.u + 0x7FFFu + ((v.u >> 16) & 1u)) >> 16);
}

__device__ __forceinline__ uint32_t pack2bf(float a, float b) {
  __hip_bfloat162 h = __float22bfloat162_rn(float2{a, b});
  union { __hip_bfloat162 h; uint32_t u; } c; c.h = h;
  return c.u;
}

#if defined(__has_builtin)
#if __has_builtin(__builtin_amdgcn_exp2f)
#define FAST_EXP2(x) __builtin_amdgcn_exp2f(x)
#endif
#endif
#ifndef FAST_EXP2
#define FAST_EXP2(x) exp2f(x)
#endif

// async global->LDS, 16B per lane; LDS dest = wave-uniform base + lane*16
__device__ __forceinline__ void glds16(const void* g, void* l) {
  __builtin_amdgcn_global_load_lds(
      (const __attribute__((address_space(1))) unsigned int*)g,
      (__attribute__((address_space(3))) unsigned int*)l, 16, 0, 0);
}

// ---------------- fused prep: rope tables + weight cast + rmsnorm ----------
// flat grid, block-uniform branch:
//   [0,256)        rope tables (fp64 trig)
//   [256,6400)     weight cast+transpose f32[1024][N] -> bf16[N][1024]
//   [6400,10496)   rmsnorm + bf16 cast
__global__ __launch_bounds__(256) void prep_kernel(
    const float* __restrict__ xa, const float* __restrict__ xx,
    const float* __restrict__ ga, const float* __restrict__ gx,
    const float* __restrict__ wqa, const float* __restrict__ wqx,
    const float* __restrict__ wkva, const float* __restrict__ wkvx,
    const float* __restrict__ woa, const float* __restrict__ wox,
    unsigned short* __restrict__ XN, unsigned short* __restrict__ WQT,
    unsigned short* __restrict__ WKVT, unsigned short* __restrict__ WOT,
    float* __restrict__ cosT, float* __restrict__ sinT) {
  __shared__ float tile[32][33];
  __shared__ float red[4];
  int bid = blockIdx.x, t = threadIdx.x;
  if (bid < 256) {
    int idx = bid * 256 + t;                    // exactly NSEQ*32
    int pos = idx >> 5, i = idx & 31;
    double inv = pow(10000.0, -(double)i / 32.0);
    double ang = (double)(2 * pos) * inv;       // t = pos * (4096/2048)
    cosT[idx] = (float)cos(ang);
    sinT[idx] = (float)sin(ang);
  } else if (bid < 6400) {
    int b = bid - 256;
    int z = b >> 10, yx = b & 1023;
    int n0 = (yx >> 5) * 32, k0 = (yx & 31) * 32;
    int s = z & 1, ty = z >> 1;
    int N = (ty == 1) ? 512 : 1024;
    if (n0 >= N) return;                        // block-uniform
    const float* src = (z == 0) ? wqa : (z == 1) ? wqx : (z == 2) ? wkva
                     : (z == 3) ? wkvx : (z == 4) ? woa : wox;
    unsigned short* dst = (ty == 0) ? WQT + (size_t)s * 1024 * 1024
                        : (ty == 1) ? WKVT + (size_t)s * 512 * 1024
                                    : WOT + (size_t)s * 1024 * 1024;
    int r = t >> 3, c4 = (t & 7) * 4;
    f32x4 v = *(const f32x4*)(src + (size_t)(k0 + r) * N + n0 + c4);
    tile[r][c4 + 0] = v.x; tile[r][c4 + 1] = v.y;
    tile[r][c4 + 2] = v.z; tile[r][c4 + 3] = v.w;
    __syncthreads();
    int nn = t >> 3, kk = (t & 7) * 4;
    bf16x4 o;
    o.x = (short)f2bf(tile[kk + 0][nn]);
    o.y = (short)f2bf(tile[kk + 1][nn]);
    o.z = (short)f2bf(tile[kk + 2][nn]);
    o.w = (short)f2bf(tile[kk + 3][nn]);
    *(bf16x4*)(dst + (size_t)(n0 + nn) * 1024 + k0 + kk) = o;
  } else {
    int b = bid - 6400;
    int s = b >> 11, row = b & 2047;
    const float* src = (s == 0 ? xa : xx) + (size_t)row * DIMM;
    const float* g = (s == 0 ? ga : gx);
    f32x4 v = *(const f32x4*)(src + t * 4);
    float ss = v.x * v.x + v.y * v.y + v.z * v.z + v.w * v.w;
#pragma unroll
    for (int o = 32; o > 0; o >>= 1) ss += __shfl_xor(ss, o, 64);
    if ((t & 63) == 0) red[t >> 6] = ss;
    __syncthreads();
    float tot = red[0] + red[1] + red[2] + red[3];
    float rs = rsqrtf(tot * (1.0f / DIMM) + 1e-6f);
    f32x4 gv = *(const f32x4*)(g + t * 4);
    bf16x4 o;
    o.x = (short)f2bf(v.x * rs * gv.x);
    o.y = (short)f2bf(v.y * rs * gv.y);
    o.z = (short)f2bf(v.z * rs * gv.z);
    o.w = (short)f2bf(v.w * rs * gv.w);
    *(bf16x4*)(XN + ((size_t)s * NSEQ + row) * DIMM + t * 4) = o;
  }
}

// ---- shared 128x128x(K=1024) bf16 NT GEMM mainloop (BK=32, 4 waves) -------
// Staging via global_load_lds (16B/lane): thread t's LDS slot = t*16 bytes,
// which matches [row=t>>2][col=(t&3)*8] of the 128x32 tile.
__device__ __forceinline__ void gemm128_mainloop(
    const unsigned short* __restrict__ Ag, const unsigned short* __restrict__ Bg,
    unsigned short* As, unsigned short* Bs, f32x4 acc[4][4]) {
  int t = threadIdx.x;
  int lane = t & 63, wid = t >> 6;
  int wm = (wid >> 1) * 64, wn = (wid & 1) * 64;
  int l15 = lane & 15, quad = lane >> 4;
  int srow = t >> 2, sko = (t & 3) * 8;
  const unsigned short* ga = Ag + (size_t)srow * 1024 + sko;
  const unsigned short* gb = Bg + (size_t)srow * 1024 + sko;
  unsigned short* la = As + t * 8;
  unsigned short* lb = Bs + t * 8;
#pragma unroll
  for (int mi = 0; mi < 4; ++mi)
#pragma unroll
    for (int j = 0; j < 4; ++j) acc[mi][j] = (f32x4){0.f, 0.f, 0.f, 0.f};
  for (int kt = 0; kt < 32; ++kt) {
    int k0 = kt * 32;
    __syncthreads();                       // prev tile's frag reads done
    glds16(ga + k0, la);
    glds16(ga + 64 * 1024 + k0, la + 2048);
    glds16(gb + k0, lb);
    glds16(gb + 64 * 1024 + k0, lb + 2048);
    __syncthreads();                       // drains vmcnt -> LDS visible
    bf16x8 af[4], bfr[4];
#pragma unroll
    for (int mi = 0; mi < 4; ++mi)
      af[mi] = *(const bf16x8*)(As + (wm + mi * 16 + l15) * 32 + quad * 8);
#pragma unroll
    for (int j = 0; j < 4; ++j)
      bfr[j] = *(const bf16x8*)(Bs + (wn + j * 16 + l15) * 32 + quad * 8);
#pragma unroll
    for (int mi = 0; mi < 4; ++mi)
#pragma unroll
      for (int j = 0; j < 4; ++j)
        acc[mi][j] = __builtin_amdgcn_mfma_f32_16x16x32_bf16(af[mi], bfr[j],
                                                             acc[mi][j], 0, 0, 0);
  }
}

// ------ QKV GEMM: A=[an;xn] (4096x1024), N=1536 (Q 1024 | K 256 | V 256) ---
// Epilogue: RoPE on q/k; q also carries both softmax scales AND log2(e).
// Layouts QB[h][jr][d], KB[h][jr][d]; V written DIRECTLY transposed to
// VT[256(h*64+d)][4096] as packed 8B stores (r-consecutive jr).
__global__ __launch_bounds__(256) void gemm_qkv_kernel(
    const unsigned short* __restrict__ XN, const unsigned short* __restrict__ WQT,
    const unsigned short* __restrict__ WKVT, const float* __restrict__ cosT,
    const float* __restrict__ sinT, unsigned short* __restrict__ QB,
    unsigned short* __restrict__ KB, unsigned short* __restrict__ VT) {
  __shared__ unsigned short As[128 * 32], Bs[128 * 32];
  int n0 = blockIdx.x * 128, m0 = blockIdx.y * 128;
  int s = (m0 >= 2048) ? 1 : 0;
  const unsigned short* Ag = XN + (size_t)m0 * 1024;
  const unsigned short* Bg = (n0 < 1024)
      ? WQT + (size_t)s * 1024 * 1024 + (size_t)n0 * 1024
      : WKVT + (size_t)s * 512 * 1024 + (size_t)(n0 - 1024) * 1024;
  f32x4 acc[4][4];
  gemm128_mainloop(Ag, Bg, As, Bs, acc);
  int t = threadIdx.x, lane = t & 63, wid = t >> 6;
  int wm = (wid >> 1) * 64, wn = (wid & 1) * 64;
  int l15 = lane & 15, quad = lane >> 4;
  int coln = n0 + wn;                     // 64-aligned -> head-uniform per wave
  if (coln < 1280) {
    bool isq = coln < 1024;
    float sc = isq ? (1.4426950408889634f / 64.0f) : 1.0f;  // 1/64 * log2(e)
    unsigned short* dstBase;
    if (isq) dstBase = QB + (size_t)(coln >> 6) * NJ * 64;
    else     dstBase = KB + (size_t)((coln - 1024) >> 6) * NJ * 64;
#pragma unroll
    for (int mi = 0; mi < 4; ++mi)
#pragma unroll
      for (int r = 0; r < 4; ++r) {
        int jr = m0 + wm + mi * 16 + quad * 4 + r;   // joint row (a:0..2047, x:2048..)
        int pos = jr & 2047;
#pragma unroll
        for (int jp = 0; jp < 2; ++jp) {             // d = jp*16+l15 pairs with d+32
          int i = jp * 16 + l15;
          float c = cosT[pos * 32 + i], sn = sinT[pos * 32 + i];
          float x1 = acc[mi][jp][r], x2 = acc[mi][jp + 2][r];
          dstBase[(size_t)jr * 64 + jp * 16 + l15]      = f2bf((x1 * c - x2 * sn) * sc);
          dstBase[(size_t)jr * 64 + 32 + jp * 16 + l15] = f2bf((x2 * c + x1 * sn) * sc);
        }
      }
  } else {
    // V: write straight to VT[d][jr] -- acc[mi][j][0..3] are 4 consecutive jr
    int cvb = coln - 1280;
#pragma unroll
    for (int mi = 0; mi < 4; ++mi)
#pragma unroll
      for (int j = 0; j < 4; ++j) {
        int d = cvb + j * 16 + l15;                  // 0..255 = hk*64 + dh
        int jr0 = m0 + wm + mi * 16 + quad * 4;
        union { bf16x4 v; uint32_t u[2]; } pv;
        pv.u[0] = pack2bf(acc[mi][j][0], acc[mi][j][1]);
        pv.u[1] = pack2bf(acc[mi][j][2], acc[mi][j][3]);
        *(bf16x4*)(VT + (size_t)d * NJ + jr0) = pv.v;
      }
  }
}

// ------------- flash attention: 128 q-rows x 1 head per block --------------
// Wave w: qsel = w>>1 picks 64 q rows (q0 = qt*128 + qsel*64, mi stride 16),
// ksel = w&1 picks the 32-key half. NO LDS staging: K/V are L2-resident
// (4 MB total = one XCD L2). K frag rows g(jb,l15) loaded per-lane from KB;
// V^T frags 16B-contiguous from VT. Register double-buffer, 2 tiles in
// flight, loads issued one compute phase ahead; no barrier in main loop.
// Lane (q=l15, quad)'s exp'd S^T values = keys 32*ksel+8*quad+0..7 -> direct
// K=32 PV B-frag. lsum via ones-row MFMA. Final ksel-pair combine via small
// LDS exchange (1 barrier).
__global__ __launch_bounds__(256, 2) void attn_kernel(
    const unsigned short* __restrict__ QB, const unsigned short* __restrict__ KB,
    const unsigned short* __restrict__ VT, unsigned short* __restrict__ AT) {
  __shared__ __align__(16) float comb[2][64 * 68];   // per-qsel exchange
  int h = blockIdx.y, qt = blockIdx.x;
  int hk = h & 3;                               // jnp.tile -> kv head = h % 4
  int t = threadIdx.x, lane = t & 63, w = t >> 6;
  int l15 = lane & 15, quad = lane >> 4;
  int qsel = w >> 1, ksel = w & 1;
  int q0 = qt * 128 + qsel * 64;                // wave's q rows: q0 + mi*16 + l15
  bf16x8 qf[4][2];
#pragma unroll
  for (int mi = 0; mi < 4; ++mi) {
    const unsigned short* qp = QB + ((size_t)h * NJ + q0 + mi * 16 + l15) * 64;
    qf[mi][0] = *(const bf16x8*)(qp + quad * 8);
    qf[mi][1] = *(const bf16x8*)(qp + 32 + quad * 8);
  }
  f32x4 oT[4][4];                               // O^T partial: [mi][db], keys of sb=ksel
  f32x4 oL[4];                                  // ones-row accum (row0 = lsum partial)
#pragma unroll
  for (int mi = 0; mi < 4; ++mi) {
    oL[mi] = (f32x4){0.f, 0.f, 0.f, 0.f};
#pragma unroll
    for (int db = 0; db < 4; ++db) oT[mi][db] = (f32x4){0.f, 0.f, 0.f, 0.f};
  }
  // ones A-frag for K=32: A[m][k] = (m==0) ? 1.0 : 0
  bf16x8 vone;
  {
    short one = (l15 == 0) ? (short)0x3F80 : (short)0;
    vone = (bf16x8){one, one, one, one, one, one, one, one};
  }
  const unsigned short* Kg = KB + (size_t)hk * NJ * 64;   // [key][d]
  const unsigned short* Vg = VT + (size_t)hk * 64 * NJ;   // [d][key]
  // per-lane K rows for this wave's jb pair {2*ksel, 2*ksel+1}:
  // g(jb, m) = 32*(jb>>1) + 8*(m>>2) + 4*(jb&1) + (m&3)
  int g0 = 32 * ksel + 8 * (l15 >> 2) + (l15 & 3);        // jj = 0
  const unsigned short* kp0 = Kg + (size_t)g0 * 64 + quad * 8;        // jj=0
  const unsigned short* kp1 = Kg + (size_t)(g0 + 4) * 64 + quad * 8;  // jj=1
  const unsigned short* vp0 = Vg + (size_t)(0 * 16 + l15) * NJ + ksel * 32 + quad * 8;
  const unsigned short* vp1 = Vg + (size_t)(1 * 16 + l15) * NJ + ksel * 32 + quad * 8;
  const unsigned short* vp2 = Vg + (size_t)(2 * 16 + l15) * NJ + ksel * 32 + quad * 8;
  const unsigned short* vp3 = Vg + (size_t)(3 * 16 + l15) * NJ + ksel * 32 + quad * 8;

  struct KV { bf16x8 k00, k01, k10, k11, v0, v1, v2, v3; };

#define LOADKV(F, KT) do {                                               \
    size_t ko_ = (size_t)(KT) * 4096;                                    \
    int vo_ = (KT) * 64;                                                 \
    (F).k00 = *(const bf16x8*)(kp0 + ko_);                               \
    (F).k01 = *(const bf16x8*)(kp0 + ko_ + 32);                          \
    (F).k10 = *(const bf16x8*)(kp1 + ko_);                               \
    (F).k11 = *(const bf16x8*)(kp1 + ko_ + 32);                          \
    (F).v0  = *(const bf16x8*)(vp0 + vo_);                               \
    (F).v1  = *(const bf16x8*)(vp1 + vo_);                               \
    (F).v2  = *(const bf16x8*)(vp2 + vo_);                               \
    (F).v3  = *(const bf16x8*)(vp3 + vo_);                               \
  } while (0)

#define COMPUTE(F) do {                                                  \
    f32x4 sx_[4][2];                                                     \
    _Pragma("unroll")                                                    \
    for (int mi = 0; mi < 4; ++mi) {                                     \
      f32x4 z0 = (f32x4){0.f, 0.f, 0.f, 0.f};                            \
      z0 = __builtin_amdgcn_mfma_f32_16x16x32_bf16((F).k00, qf[mi][0], z0, 0, 0, 0); \
      z0 = __builtin_amdgcn_mfma_f32_16x16x32_bf16((F).k01, qf[mi][1], z0, 0, 0, 0); \
      sx_[mi][0] = z0;                                                   \
      f32x4 z1 = (f32x4){0.f, 0.f, 0.f, 0.f};                            \
      z1 = __builtin_amdgcn_mfma_f32_16x16x32_bf16((F).k10, qf[mi][0], z1, 0, 0, 0); \
      z1 = __builtin_amdgcn_mfma_f32_16x16x32_bf16((F).k11, qf[mi][1], z1, 0, 0, 0); \
      sx_[mi][1] = z1;                                                   \
    }                                                                    \
    bf16x8 pb_[4];                                                       \
    _Pragma("unroll")                                                    \
    for (int mi = 0; mi < 4; ++mi) {                                     \
      union { bf16x8 v; uint32_t u[4]; } pk_;                            \
      pk_.u[0] = pack2bf(FAST_EXP2(sx_[mi][0][0]), FAST_EXP2(sx_[mi][0][1])); \
      pk_.u[1] = pack2bf(FAST_EXP2(sx_[mi][0][2]), FAST_EXP2(sx_[mi][0][3])); \
      pk_.u[2] = pack2bf(FAST_EXP2(sx_[mi][1][0]), FAST_EXP2(sx_[mi][1][1])); \
      pk_.u[3] = pack2bf(FAST_EXP2(sx_[mi][1][2]), FAST_EXP2(sx_[mi][1][3])); \
      pb_[mi] = pk_.v;                                                   \
    }                                                                    \
    _Pragma("unroll")                                                    \
    for (int mi = 0; mi < 4; ++mi) {                                     \
      oT[mi][0] = __builtin_amdgcn_mfma_f32_16x16x32_bf16((F).v0, pb_[mi], oT[mi][0], 0, 0, 0); \
      oT[mi][1] = __builtin_amdgcn_mfma_f32_16x16x32_bf16((F).v1, pb_[mi], oT[mi][1], 0, 0, 0); \
      oT[mi][2] = __builtin_amdgcn_mfma_f32_16x16x32_bf16((F).v2, pb_[mi], oT[mi][2], 0, 0, 0); \
      oT[mi][3] = __builtin_amdgcn_mfma_f32_16x16x32_bf16((F).v3, pb_[mi], oT[mi][3], 0, 0, 0); \
      oL[mi] = __builtin_amdgcn_mfma_f32_16x16x32_bf16(vone, pb_[mi], oL[mi], 0, 0, 0); \
    }                                                                    \
  } while (0)

  KV fA, fB;
  LOADKV(fA, 0);
  LOADKV(fB, 1);
  for (int kt = 0; kt < 64; kt += 2) {
    COMPUTE(fA);                                // tile kt
    LOADKV(fA, (kt + 2) & 63);                  // wrap: harmless reload at end
    COMPUTE(fB);                                // tile kt+1
    LOADKV(fB, (kt + 3) & 63);
  }
#undef LOADKV
#undef COMPUTE

  // ---- combine key-split partials across wave pairs (ksel 0 <- 1) ----
  // lsum: row0 lives on quad==0; quad-reduce first so every lane holds the
  // partial for q = l15 of each mi.
  float ls[4];
#pragma unroll
  for (int mi = 0; mi < 4; ++mi) {
    float s = oL[mi][0];
    s += __shfl_xor(s, 16, 64);
    s += __shfl_xor(s, 32, 64);
    ls[mi] = s;
  }
  float* xb = comb[qsel];
  if (ksel == 1) {
    f32x4* dst = (f32x4*)xb + (size_t)lane * 16;
#pragma unroll
    for (int mi = 0; mi < 4; ++mi)
#pragma unroll
      for (int db = 0; db < 4; ++db) dst[mi * 4 + db] = oT[mi][db];
    float* dl = xb + 64 * 64 + lane * 4;
#pragma unroll
    for (int mi = 0; mi < 4; ++mi) dl[mi] = ls[mi];
  }
  __syncthreads();
  if (ksel == 0) {
    const f32x4* src = (const f32x4*)xb + (size_t)lane * 16;
    const float* sl = xb + 64 * 64 + lane * 4;
#pragma unroll
    for (int mi = 0; mi < 4; ++mi) {
      float inv = 1.0f / (ls[mi] + sl[mi]);
      int qrow = q0 + mi * 16 + l15;
#pragma unroll
      for (int db = 0; db < 4; ++db) {
        f32x4 o = oT[mi][db] + src[mi * 4 + db];
        union { bf16x4 v; uint32_t u[2]; } ov;
        ov.u[0] = pack2bf(o[0] * inv, o[1] * inv);
        ov.u[1] = pack2bf(o[2] * inv, o[3] * inv);
        *(bf16x4*)(AT + (size_t)qrow * DIMM + h * 64 + db * 16 + quad * 4) = ov.v;
      }
    }
  }
}

// ---------------- output GEMM: AT (4096x1024) @ Wout^T + bias -> f32 -------
__global__ __launch_bounds__(256) void gemm_out_kernel(
    const unsigned short* __restrict__ AT, const unsigned short* __restrict__ WOT,
    const float* __restrict__ ba, const float* __restrict__ bx,
    float* __restrict__ out) {
  __shared__ unsigned short As[128 * 32], Bs[128 * 32];
  int n0 = blockIdx.x * 128, m0 = blockIdx.y * 128;
  int s = (m0 >= 2048) ? 1 : 0;                 // 0 = a-stream rows, 1 = x
  const unsigned short* Ag = AT + (size_t)m0 * 1024;
  const unsigned short* Bg = WOT + (size_t)s * 1024 * 1024 + (size_t)n0 * 1024;
  f32x4 acc[4][4];
  gemm128_mainloop(Ag, Bg, As, Bs, acc);
  int t = threadIdx.x, lane = t & 63, wid = t >> 6;
  int wm = (wid >> 1) * 64, wn = (wid & 1) * 64;
  int l15 = lane & 15, quad = lane >> 4;
  const float* bias = s ? bx : ba;
  // d_out = [out_x (2048x1024) | out_a (2048x1024)]
  float* obase = s ? (out + (size_t)(m0 - 2048) * 1024)
                   : (out + (size_t)2048 * 1024 + (size_t)m0 * 1024);
#pragma unroll
  for (int mi = 0; mi < 4; ++mi)
#pragma unroll
    for (int r = 0; r < 4; ++r) {
      int row = wm + mi * 16 + quad * 4 + r;
#pragma unroll
      for (int j = 0; j < 4; ++j) {
        int col = n0 + wn + j * 16 + l15;
        obase[(size_t)row * 1024 + col] = acc[mi][j][r] + bias[col];
      }
    }
}

// ---------------------------------------------------------------------------
extern "C" void kernel_launch(void* const* d_in, const int* in_sizes, int n_in,
                              void* d_out, int out_size, void* d_ws, size_t ws_size,
                              hipStream_t stream) {
  const float* x      = (const float*)d_in[0];
  const float* a      = (const float*)d_in[1];
  const float* g_x    = (const float*)d_in[2];
  const float* g_a    = (const float*)d_in[3];
  const float* Wq_x   = (const float*)d_in[4];
  const float* Wkv_x  = (const float*)d_in[5];
  const float* Wq_a   = (const float*)d_in[6];
  const float* Wkv_a  = (const float*)d_in[7];
  const float* Wout_x = (const float*)d_in[8];
  const float* bout_x = (const float*)d_in[9];
  const float* Wout_a = (const float*)d_in[10];
  const float* bout_a = (const float*)d_in[11];
  float* out = (float*)d_out;

  // workspace (30.5 MB). AT aliases XN (dead after gemm_qkv).
  char* ws = (char*)d_ws;
  const size_t MB = 1024 * 1024;
  unsigned short* XN   = (unsigned short*)(ws);            // 8 MB
  unsigned short* WQT  = (unsigned short*)(ws + 8 * MB);   // 4 MB
  unsigned short* WKVT = (unsigned short*)(ws + 12 * MB);  // 2 MB
  unsigned short* WOT  = (unsigned short*)(ws + 14 * MB);  // 4 MB
  unsigned short* QB   = (unsigned short*)(ws + 18 * MB);  // 8 MB
  unsigned short* KB   = (unsigned short*)(ws + 26 * MB);  // 2 MB
  unsigned short* VT   = (unsigned short*)(ws + 28 * MB);  // 2 MB
  float* cosT          = (float*)(ws + 30 * MB);           // 256 KB
  float* sinT          = (float*)(ws + 30 * MB + 262144);  // 256 KB
  unsigned short* AT   = XN;                               // alias

  prep_kernel<<<dim3(10496), dim3(256), 0, stream>>>(
      a, x, g_a, g_x, Wq_a, Wq_x, Wkv_a, Wkv_x, Wout_a, Wout_x,
      XN, WQT, WKVT, WOT, cosT, sinT);
  gemm_qkv_kernel<<<dim3(12, 32), dim3(256), 0, stream>>>(
      XN, WQT, WKVT, cosT, sinT, QB, KB, VT);
  attn_kernel<<<dim3(32, 16), dim3(256), 0, stream>>>(QB, KB, VT, AT);
  gemm_out_kernel<<<dim3(8, 32), dim3(256), 0, stream>>>(
      AT, WOT, bout_a, bout_x, out);
}

// Round 3
// 238.028 us; speedup vs baseline: 1.1383x; 1.1383x over previous
//
#include <hip/hip_runtime.h>
#include <hip/hip_bf16.h>
#include <stdint.h>
#include <math.h>

// ---------------------------------------------------------------------------
// JointAttention: dual-stream rmsnorm -> QKV proj -> RoPE -> joint attention
// over concat(a, x) (4096 tokens, 16 q-heads, 4 kv-heads tiled h%4) -> out proj.
// All matmuls in bf16 MFMA, fp32 accumulate.
//
// R11 = R9 structure (staged, permuted K LDS, reg-prefetch double-buffer)
// with the attn q-tile split 128 -> 64 to double occupancy:
//  - R9 was grid-limited: 512 blocks = 2 blocks/CU = 2 waves/SIMD, phase-
//    locked by the per-tile barrier -> neither pipe fed (Mfma 37 / VALU 44,
//    ~19% occupancy). R10 proved LDS throughput is NOT the limit (halving
//    reads gained 4%) and that direct-L2 frag gathers are far worse.
//  - R11: q-tile 64, grid 64x16 = 1024 blocks = 4 blocks/CU (LDS-capped:
//    4 x 36 KB = 147 KB) = 4 waves/SIMD. Staging traffic doubles (2 blocks
//    share each K/V tile) -- acceptable: LDS pipe was ~35% busy.
//  - Wave w: qsel=w>>1 (32 q rows), ksel=w&1 (32-key half). 18 MFMA +
//    8 ds_reads per wave-tile. Same write-side K permutation; exp'd-S^T
//    packs directly into the K=32 PV B-frag. lsum via ones-row MFMA.
//  - ksel-pair combine in-block via dead LDS buffers (stride padded to 9
//    f32x4/lane to avoid the old 32-way one-time bank conflict).
// ---------------------------------------------------------------------------

#define NSEQ 2048
#define NJ   4096
#define DIMM 1024
#define LPAD 72

typedef __attribute__((ext_vector_type(4))) float f32x4;
typedef __attribute__((ext_vector_type(8))) short bf16x8;
typedef __attribute__((ext_vector_type(4))) short bf16x4;

__device__ __forceinline__ unsigned short f2bf(float f) {
  union { float f; uint32_t u; } v; v.f = f;
  return (unsigned short)((v.u + 0x7FFFu + ((v.u >> 16) & 1u)) >> 16);
}

__device__ __forceinline__ uint32_t pack2bf(float a, float b) {
  __hip_bfloat162 h = __float22bfloat162_rn(float2{a, b});
  union { __hip_bfloat162 h; uint32_t u; } c; c.h = h;
  return c.u;
}

#if defined(__has_builtin)
#if __has_builtin(__builtin_amdgcn_exp2f)
#define FAST_EXP2(x) __builtin_amdgcn_exp2f(x)
#endif
#endif
#ifndef FAST_EXP2
#define FAST_EXP2(x) exp2f(x)
#endif

// async global->LDS, 16B per lane; LDS dest = wave-uniform base + lane*16
__device__ __forceinline__ void glds16(const void* g, void* l) {
  __builtin_amdgcn_global_load_lds(
      (const __attribute__((address_space(1))) unsigned int*)g,
      (__attribute__((address_space(3))) unsigned int*)l, 16, 0, 0);
}

// ---------------- fused prep: rope tables + weight cast + rmsnorm ----------
// flat grid, block-uniform branch:
//   [0,256)        rope tables (fp64 trig)
//   [256,6400)     weight cast+transpose f32[1024][N] -> bf16[N][1024]
//   [6400,10496)   rmsnorm + bf16 cast
__global__ __launch_bounds__(256) void prep_kernel(
    const float* __restrict__ xa, const float* __restrict__ xx,
    const float* __restrict__ ga, const float* __restrict__ gx,
    const float* __restrict__ wqa, const float* __restrict__ wqx,
    const float* __restrict__ wkva, const float* __restrict__ wkvx,
    const float* __restrict__ woa, const float* __restrict__ wox,
    unsigned short* __restrict__ XN, unsigned short* __restrict__ WQT,
    unsigned short* __restrict__ WKVT, unsigned short* __restrict__ WOT,
    float* __restrict__ cosT, float* __restrict__ sinT) {
  __shared__ float tile[32][33];
  __shared__ float red[4];
  int bid = blockIdx.x, t = threadIdx.x;
  if (bid < 256) {
    int idx = bid * 256 + t;                    // exactly NSEQ*32
    int pos = idx >> 5, i = idx & 31;
    double inv = pow(10000.0, -(double)i / 32.0);
    double ang = (double)(2 * pos) * inv;       // t = pos * (4096/2048)
    cosT[idx] = (float)cos(ang);
    sinT[idx] = (float)sin(ang);
  } else if (bid < 6400) {
    int b = bid - 256;
    int z = b >> 10, yx = b & 1023;
    int n0 = (yx >> 5) * 32, k0 = (yx & 31) * 32;
    int s = z & 1, ty = z >> 1;
    int N = (ty == 1) ? 512 : 1024;
    if (n0 >= N) return;                        // block-uniform
    const float* src = (z == 0) ? wqa : (z == 1) ? wqx : (z == 2) ? wkva
                     : (z == 3) ? wkvx : (z == 4) ? woa : wox;
    unsigned short* dst = (ty == 0) ? WQT + (size_t)s * 1024 * 1024
                        : (ty == 1) ? WKVT + (size_t)s * 512 * 1024
                                    : WOT + (size_t)s * 1024 * 1024;
    int r = t >> 3, c4 = (t & 7) * 4;
    f32x4 v = *(const f32x4*)(src + (size_t)(k0 + r) * N + n0 + c4);
    tile[r][c4 + 0] = v.x; tile[r][c4 + 1] = v.y;
    tile[r][c4 + 2] = v.z; tile[r][c4 + 3] = v.w;
    __syncthreads();
    int nn = t >> 3, kk = (t & 7) * 4;
    bf16x4 o;
    o.x = (short)f2bf(tile[kk + 0][nn]);
    o.y = (short)f2bf(tile[kk + 1][nn]);
    o.z = (short)f2bf(tile[kk + 2][nn]);
    o.w = (short)f2bf(tile[kk + 3][nn]);
    *(bf16x4*)(dst + (size_t)(n0 + nn) * 1024 + k0 + kk) = o;
  } else {
    int b = bid - 6400;
    int s = b >> 11, row = b & 2047;
    const float* src = (s == 0 ? xa : xx) + (size_t)row * DIMM;
    const float* g = (s == 0 ? ga : gx);
    f32x4 v = *(const f32x4*)(src + t * 4);
    float ss = v.x * v.x + v.y * v.y + v.z * v.z + v.w * v.w;
#pragma unroll
    for (int o = 32; o > 0; o >>= 1) ss += __shfl_xor(ss, o, 64);
    if ((t & 63) == 0) red[t >> 6] = ss;
    __syncthreads();
    float tot = red[0] + red[1] + red[2] + red[3];
    float rs = rsqrtf(tot * (1.0f / DIMM) + 1e-6f);
    f32x4 gv = *(const f32x4*)(g + t * 4);
    bf16x4 o;
    o.x = (short)f2bf(v.x * rs * gv.x);
    o.y = (short)f2bf(v.y * rs * gv.y);
    o.z = (short)f2bf(v.z * rs * gv.z);
    o.w = (short)f2bf(v.w * rs * gv.w);
    *(bf16x4*)(XN + ((size_t)s * NSEQ + row) * DIMM + t * 4) = o;
  }
}

// ---- shared 128x128x(K=1024) bf16 NT GEMM mainloop (BK=32, 4 waves) -------
// Staging via global_load_lds (16B/lane): thread t's LDS slot = t*16 bytes,
// which matches [row=t>>2][col=(t&3)*8] of the 128x32 tile.
__device__ __forceinline__ void gemm128_mainloop(
    const unsigned short* __restrict__ Ag, const unsigned short* __restrict__ Bg,
    unsigned short* As, unsigned short* Bs, f32x4 acc[4][4]) {
  int t = threadIdx.x;
  int lane = t & 63, wid = t >> 6;
  int wm = (wid >> 1) * 64, wn = (wid & 1) * 64;
  int l15 = lane & 15, quad = lane >> 4;
  int srow = t >> 2, sko = (t & 3) * 8;
  const unsigned short* ga = Ag + (size_t)srow * 1024 + sko;
  const unsigned short* gb = Bg + (size_t)srow * 1024 + sko;
  unsigned short* la = As + t * 8;
  unsigned short* lb = Bs + t * 8;
#pragma unroll
  for (int mi = 0; mi < 4; ++mi)
#pragma unroll
    for (int j = 0; j < 4; ++j) acc[mi][j] = (f32x4){0.f, 0.f, 0.f, 0.f};
  for (int kt = 0; kt < 32; ++kt) {
    int k0 = kt * 32;
    __syncthreads();                       // prev tile's frag reads done
    glds16(ga + k0, la);
    glds16(ga + 64 * 1024 + k0, la + 2048);
    glds16(gb + k0, lb);
    glds16(gb + 64 * 1024 + k0, lb + 2048);
    __syncthreads();                       // drains vmcnt -> LDS visible
    bf16x8 af[4], bfr[4];
#pragma unroll
    for (int mi = 0; mi < 4; ++mi)
      af[mi] = *(const bf16x8*)(As + (wm + mi * 16 + l15) * 32 + quad * 8);
#pragma unroll
    for (int j = 0; j < 4; ++j)
      bfr[j] = *(const bf16x8*)(Bs + (wn + j * 16 + l15) * 32 + quad * 8);
#pragma unroll
    for (int mi = 0; mi < 4; ++mi)
#pragma unroll
      for (int j = 0; j < 4; ++j)
        acc[mi][j] = __builtin_amdgcn_mfma_f32_16x16x32_bf16(af[mi], bfr[j],
                                                             acc[mi][j], 0, 0, 0);
  }
}

// ------ QKV GEMM: A=[an;xn] (4096x1024), N=1536 (Q 1024 | K 256 | V 256) ---
// Epilogue: RoPE on q/k; q also carries both softmax scales AND log2(e).
// Layouts QB[h][jr][d], KB[h][jr][d]; V written DIRECTLY transposed to
// VT[256(h*64+d)][4096] as packed 8B stores (r-consecutive jr).
__global__ __launch_bounds__(256) void gemm_qkv_kernel(
    const unsigned short* __restrict__ XN, const unsigned short* __restrict__ WQT,
    const unsigned short* __restrict__ WKVT, const float* __restrict__ cosT,
    const float* __restrict__ sinT, unsigned short* __restrict__ QB,
    unsigned short* __restrict__ KB, unsigned short* __restrict__ VT) {
  __shared__ unsigned short As[128 * 32], Bs[128 * 32];
  int n0 = blockIdx.x * 128, m0 = blockIdx.y * 128;
  int s = (m0 >= 2048) ? 1 : 0;
  const unsigned short* Ag = XN + (size_t)m0 * 1024;
  const unsigned short* Bg = (n0 < 1024)
      ? WQT + (size_t)s * 1024 * 1024 + (size_t)n0 * 1024
      : WKVT + (size_t)s * 512 * 1024 + (size_t)(n0 - 1024) * 1024;
  f32x4 acc[4][4];
  gemm128_mainloop(Ag, Bg, As, Bs, acc);
  int t = threadIdx.x, lane = t & 63, wid = t >> 6;
  int wm = (wid >> 1) * 64, wn = (wid & 1) * 64;
  int l15 = lane & 15, quad = lane >> 4;
  int coln = n0 + wn;                     // 64-aligned -> head-uniform per wave
  if (coln < 1280) {
    bool isq = coln < 1024;
    float sc = isq ? (1.4426950408889634f / 64.0f) : 1.0f;  // 1/64 * log2(e)
    unsigned short* dstBase;
    if (isq) dstBase = QB + (size_t)(coln >> 6) * NJ * 64;
    else     dstBase = KB + (size_t)((coln - 1024) >> 6) * NJ * 64;
#pragma unroll
    for (int mi = 0; mi < 4; ++mi)
#pragma unroll
      for (int r = 0; r < 4; ++r) {
        int jr = m0 + wm + mi * 16 + quad * 4 + r;   // joint row (a:0..2047, x:2048..)
        int pos = jr & 2047;
#pragma unroll
        for (int jp = 0; jp < 2; ++jp) {             // d = jp*16+l15 pairs with d+32
          int i = jp * 16 + l15;
          float c = cosT[pos * 32 + i], sn = sinT[pos * 32 + i];
          float x1 = acc[mi][jp][r], x2 = acc[mi][jp + 2][r];
          dstBase[(size_t)jr * 64 + jp * 16 + l15]      = f2bf((x1 * c - x2 * sn) * sc);
          dstBase[(size_t)jr * 64 + 32 + jp * 16 + l15] = f2bf((x2 * c + x1 * sn) * sc);
        }
      }
  } else {
    // V: write straight to VT[d][jr] -- acc[mi][j][0..3] are 4 consecutive jr
    int cvb = coln - 1280;
#pragma unroll
    for (int mi = 0; mi < 4; ++mi)
#pragma unroll
      for (int j = 0; j < 4; ++j) {
        int d = cvb + j * 16 + l15;                  // 0..255 = hk*64 + dh
        int jr0 = m0 + wm + mi * 16 + quad * 4;
        union { bf16x4 v; uint32_t u[2]; } pv;
        pv.u[0] = pack2bf(acc[mi][j][0], acc[mi][j][1]);
        pv.u[1] = pack2bf(acc[mi][j][2], acc[mi][j][3]);
        *(bf16x4*)(VT + (size_t)d * NJ + jr0) = pv.v;
      }
  }
}

// ------------- flash attention: 64 q-rows x 1 head per block ---------------
// Grid 64x16 = 1024 blocks = 4 blocks/CU (LDS-capped) = 4 waves/SIMD.
// Wave w: qsel = w>>1 picks 32 q rows (q0 + qsel*32 + mi*16 + l15, mi=0,1),
// ksel = w&1 picks the 32-key half (jb pair {2ksel, 2ksel+1} = sb ksel).
// K staged PERMUTED (key k -> LDS row p(k)); kf reads use plain rows
// jb*16+l15 so row m of block jb holds key g(jb,m). Lane (q,l15)'s exp'd
// S^T values for its sb are keys 32sb+8q+0..7 -> direct K=32 PV B-frag.
// V natural order; V^T A-frags contiguous bf16x8. lsum via ones-row MFMA.
// K/V LDS double-buffered (pad 72 = 16B-aligned rows), 1 barrier/tile.
// Key-split O^T/lsum partials combined once at the end via the LDS buffers.
__global__ __launch_bounds__(256, 4) void attn_kernel(
    const unsigned short* __restrict__ QB, const unsigned short* __restrict__ KB,
    const unsigned short* __restrict__ VT, unsigned short* __restrict__ AT) {
  __shared__ __align__(16) unsigned short Ks[2][64 * LPAD];
  __shared__ __align__(16) unsigned short Vs[2][64 * LPAD];
  int h = blockIdx.y, qt = blockIdx.x;
  int hk = h & 3;                               // jnp.tile -> kv head = h % 4
  int t = threadIdx.x, lane = t & 63, w = t >> 6;
  int l15 = lane & 15, quad = lane >> 4;
  int qsel = w >> 1, ksel = w & 1;
  int q0 = qt * 64 + qsel * 32;                 // wave's q rows: q0 + mi*16 + l15
  bf16x8 qf[2][2];
#pragma unroll
  for (int mi = 0; mi < 2; ++mi) {
    const unsigned short* qp = QB + ((size_t)h * NJ + q0 + mi * 16 + l15) * 64;
    qf[mi][0] = *(const bf16x8*)(qp + quad * 8);
    qf[mi][1] = *(const bf16x8*)(qp + 32 + quad * 8);
  }
  f32x4 oT[2][4];                               // O^T partial: [mi][db], keys of sb=ksel
  f32x4 oL[2];                                  // ones-row accum (row0 = lsum partial)
#pragma unroll
  for (int mi = 0; mi < 2; ++mi) {
    oL[mi] = (f32x4){0.f, 0.f, 0.f, 0.f};
#pragma unroll
    for (int db = 0; db < 4; ++db) oT[mi][db] = (f32x4){0.f, 0.f, 0.f, 0.f};
  }
  // ones A-frag for K=32: A[m][k] = (m==0) ? 1.0 : 0
  bf16x8 vone;
  {
    short one = (l15 == 0) ? (short)0x3F80 : (short)0;
    vone = (bf16x8){one, one, one, one, one, one, one, one};
  }
  const unsigned short* Kg = KB + (size_t)hk * NJ * 64;   // [key][d]
  const unsigned short* Vg = VT + (size_t)hk * 64 * NJ;   // [d][key]
  int ky = t >> 3, dof = (t & 7) * 8;
  // write-side permutation: key k -> LDS row p(k); p(k+32) = p(k)+32
  int pky = (ky & 0x23) | ((ky & 0x18) >> 1) | ((ky & 0x04) << 2);
  const unsigned short* KgA = Kg + (size_t)ky * 64 + dof;        // +tile*4096
  const unsigned short* KgB = Kg + (size_t)(32 + ky) * 64 + dof;
  const unsigned short* VgA = Vg + (size_t)ky * NJ + dof;        // +tile*64
  const unsigned short* VgB = Vg + (size_t)(32 + ky) * NJ + dof;
  // preload tile 0 -> buf0; prefetch tile 1 -> regs
  bf16x8 kr0 = *(const bf16x8*)(KgA);
  bf16x8 kr1 = *(const bf16x8*)(KgB);
  bf16x8 vr0 = *(const bf16x8*)(VgA);
  bf16x8 vr1 = *(const bf16x8*)(VgB);
  *(bf16x8*)(Ks[0] + pky * LPAD + dof) = kr0;
  *(bf16x8*)(Ks[0] + (32 + pky) * LPAD + dof) = kr1;
  *(bf16x8*)(Vs[0] + ky * LPAD + dof) = vr0;
  *(bf16x8*)(Vs[0] + (32 + ky) * LPAD + dof) = vr1;
  kr0 = *(const bf16x8*)(KgA + 4096);
  kr1 = *(const bf16x8*)(KgB + 4096);
  vr0 = *(const bf16x8*)(VgA + 64);
  vr1 = *(const bf16x8*)(VgB + 64);
  __syncthreads();
  for (int kt = 0; kt < 64; ++kt) {
    int cur = kt & 1;
    // write tile kt+1 into other buffer (covered by tile kt-1 compute);
    // issue tile kt+2 loads (drained at end-of-iter barrier).
    unsigned short* Kd = Ks[cur ^ 1];
    unsigned short* Vd = Vs[cur ^ 1];
    *(bf16x8*)(Kd + pky * LPAD + dof) = kr0;
    *(bf16x8*)(Kd + (32 + pky) * LPAD + dof) = kr1;
    *(bf16x8*)(Vd + ky * LPAD + dof) = vr0;
    *(bf16x8*)(Vd + (32 + ky) * LPAD + dof) = vr1;
    int tn = (kt + 2) & 63;                     // wrap: harmless rewrite at end
    kr0 = *(const bf16x8*)(KgA + (size_t)tn * 4096);
    kr1 = *(const bf16x8*)(KgB + (size_t)tn * 4096);
    vr0 = *(const bf16x8*)(VgA + tn * 64);
    vr1 = *(const bf16x8*)(VgB + tn * 64);
    // ---- compute tile kt from buf cur ----
    const unsigned short* Kc = Ks[cur];
    const unsigned short* Vc = Vs[cur];
    // QK over this wave's jb pair {2ksel, 2ksel+1}; plain rows (content
    // permuted at write time). Each kf read feeds 2 MFMAs.
    f32x4 sx[2][2];
#pragma unroll
    for (int jj = 0; jj < 2; ++jj) {
      int jb = 2 * ksel + jj;
      const unsigned short* kp = Kc + (jb * 16 + l15) * LPAD;
      bf16x8 kf0 = *(const bf16x8*)(kp + quad * 8);
      bf16x8 kf1 = *(const bf16x8*)(kp + 32 + quad * 8);
#pragma unroll
      for (int mi = 0; mi < 2; ++mi) {
        f32x4 z = (f32x4){0.f, 0.f, 0.f, 0.f};
        z = __builtin_amdgcn_mfma_f32_16x16x32_bf16(kf0, qf[mi][0], z, 0, 0, 0);
        z = __builtin_amdgcn_mfma_f32_16x16x32_bf16(kf1, qf[mi][1], z, 0, 0, 0);
        sx[mi][jj] = z;
      }
    }
    // exp (native) + pack: lane's 8 values of the wave's sb = keys
    // 32*ksel+8*quad+0..7 = exactly the 16x16x32 B-frag (k=quad*8+e, n=l15).
    bf16x8 pb[2];
#pragma unroll
    for (int mi = 0; mi < 2; ++mi) {
      union { bf16x8 v; uint32_t u[4]; } pk;
      pk.u[0] = pack2bf(FAST_EXP2(sx[mi][0][0]), FAST_EXP2(sx[mi][0][1]));
      pk.u[1] = pack2bf(FAST_EXP2(sx[mi][0][2]), FAST_EXP2(sx[mi][0][3]));
      pk.u[2] = pack2bf(FAST_EXP2(sx[mi][1][0]), FAST_EXP2(sx[mi][1][1]));
      pk.u[3] = pack2bf(FAST_EXP2(sx[mi][1][2]), FAST_EXP2(sx[mi][1][3]));
      pb[mi] = pk.v;
    }
    // PV at K=32, sb = ksel: each va read feeds 2 MFMAs
#pragma unroll
    for (int db = 0; db < 4; ++db) {
      bf16x8 va = *(const bf16x8*)(Vc + (db * 16 + l15) * LPAD + ksel * 32 + quad * 8);
      oT[0][db] = __builtin_amdgcn_mfma_f32_16x16x32_bf16(va, pb[0],
                                                          oT[0][db], 0, 0, 0);
      oT[1][db] = __builtin_amdgcn_mfma_f32_16x16x32_bf16(va, pb[1],
                                                          oT[1][db], 0, 0, 0);
    }
    // lsum rows (row0 of oL accumulates key-sums of this wave's half)
#pragma unroll
    for (int mi = 0; mi < 2; ++mi)
      oL[mi] = __builtin_amdgcn_mfma_f32_16x16x32_bf16(vone, pb[mi],
                                                       oL[mi], 0, 0, 0);
    __syncthreads();                            // reads of buf cur done; drains
  }                                             // prefetch (covered by compute)
  // ---- combine key-split partials across wave pairs (ksel 0 <- 1) ----
  // lsum: row0 lives on quad==0; quad-reduce first so every lane holds the
  // partial for q = l15 of each mi.
  float ls[2];
#pragma unroll
  for (int mi = 0; mi < 2; ++mi) {
    float s = oL[mi][0];
    s += __shfl_xor(s, 16, 64);
    s += __shfl_xor(s, 32, 64);
    ls[mi] = s;
  }
  // per-qsel scratch: qsel0 -> Ks, qsel1 -> Vs. oT in buf[0] with lane
  // stride 9 f32x4 (144 B, conflict-free); ls in buf[1].
  float* xb = (float*)(qsel == 0 ? &Ks[0][0] : &Vs[0][0]);
  float* xl = (float*)(qsel == 0 ? &Ks[1][0] : &Vs[1][0]);
  // main loop ended with __syncthreads(): all tile reads complete.
  if (ksel == 1) {
    f32x4* dst = (f32x4*)xb + (size_t)lane * 9;
#pragma unroll
    for (int mi = 0; mi < 2; ++mi)
#pragma unroll
      for (int db = 0; db < 4; ++db) dst[mi * 4 + db] = oT[mi][db];
    float* dl = xl + lane * 2;
#pragma unroll
    for (int mi = 0; mi < 2; ++mi) dl[mi] = ls[mi];
  }
  __syncthreads();
  if (ksel == 0) {
    const f32x4* src = (const f32x4*)xb + (size_t)lane * 9;
    const float* sl = xl + lane * 2;
#pragma unroll
    for (int mi = 0; mi < 2; ++mi) {
      float inv = 1.0f / (ls[mi] + sl[mi]);
      int qrow = q0 + mi * 16 + l15;
#pragma unroll
      for (int db = 0; db < 4; ++db) {
        f32x4 o = oT[mi][db] + src[mi * 4 + db];
        union { bf16x4 v; uint32_t u[2]; } ov;
        ov.u[0] = pack2bf(o[0] * inv, o[1] * inv);
        ov.u[1] = pack2bf(o[2] * inv, o[3] * inv);
        *(bf16x4*)(AT + (size_t)qrow * DIMM + h * 64 + db * 16 + quad * 4) = ov.v;
      }
    }
  }
}

// ---------------- output GEMM: AT (4096x1024) @ Wout^T + bias -> f32 -------
__global__ __launch_bounds__(256) void gemm_out_kernel(
    const unsigned short* __restrict__ AT, const unsigned short* __restrict__ WOT,
    const float* __restrict__ ba, const float* __restrict__ bx,
    float* __restrict__ out) {
  __shared__ unsigned short As[128 * 32], Bs[128 * 32];
  int n0 = blockIdx.x * 128, m0 = blockIdx.y * 128;
  int s = (m0 >= 2048) ? 1 : 0;                 // 0 = a-stream rows, 1 = x
  const unsigned short* Ag = AT + (size_t)m0 * 1024;
  const unsigned short* Bg = WOT + (size_t)s * 1024 * 1024 + (size_t)n0 * 1024;
  f32x4 acc[4][4];
  gemm128_mainloop(Ag, Bg, As, Bs, acc);
  int t = threadIdx.x, lane = t & 63, wid = t >> 6;
  int wm = (wid >> 1) * 64, wn = (wid & 1) * 64;
  int l15 = lane & 15, quad = lane >> 4;
  const float* bias = s ? bx : ba;
  // d_out = [out_x (2048x1024) | out_a (2048x1024)]
  float* obase = s ? (out + (size_t)(m0 - 2048) * 1024)
                   : (out + (size_t)2048 * 1024 + (size_t)m0 * 1024);
#pragma unroll
  for (int mi = 0; mi < 4; ++mi)
#pragma unroll
    for (int r = 0; r < 4; ++r) {
      int row = wm + mi * 16 + quad * 4 + r;
#pragma unroll
      for (int j = 0; j < 4; ++j) {
        int col = n0 + wn + j * 16 + l15;
        obase[(size_t)row * 1024 + col] = acc[mi][j][r] + bias[col];
      }
    }
}

// ---------------------------------------------------------------------------
extern "C" void kernel_launch(void* const* d_in, const int* in_sizes, int n_in,
                              void* d_out, int out_size, void* d_ws, size_t ws_size,
                              hipStream_t stream) {
  const float* x      = (const float*)d_in[0];
  const float* a      = (const float*)d_in[1];
  const float* g_x    = (const float*)d_in[2];
  const float* g_a    = (const float*)d_in[3];
  const float* Wq_x   = (const float*)d_in[4];
  const float* Wkv_x  = (const float*)d_in[5];
  const float* Wq_a   = (const float*)d_in[6];
  const float* Wkv_a  = (const float*)d_in[7];
  const float* Wout_x = (const float*)d_in[8];
  const float* bout_x = (const float*)d_in[9];
  const float* Wout_a = (const float*)d_in[10];
  const float* bout_a = (const float*)d_in[11];
  float* out = (float*)d_out;

  // workspace (30.5 MB). AT aliases XN (dead after gemm_qkv).
  char* ws = (char*)d_ws;
  const size_t MB = 1024 * 1024;
  unsigned short* XN   = (unsigned short*)(ws);            // 8 MB
  unsigned short* WQT  = (unsigned short*)(ws + 8 * MB);   // 4 MB
  unsigned short* WKVT = (unsigned short*)(ws + 12 * MB);  // 2 MB
  unsigned short* WOT  = (unsigned short*)(ws + 14 * MB);  // 4 MB
  unsigned short* QB   = (unsigned short*)(ws + 18 * MB);  // 8 MB
  unsigned short* KB   = (unsigned short*)(ws + 26 * MB);  // 2 MB
  unsigned short* VT   = (unsigned short*)(ws + 28 * MB);  // 2 MB
  float* cosT          = (float*)(ws + 30 * MB);           // 256 KB
  float* sinT          = (float*)(ws + 30 * MB + 262144);  // 256 KB
  unsigned short* AT   = XN;                               // alias

  prep_kernel<<<dim3(10496), dim3(256), 0, stream>>>(
      a, x, g_a, g_x, Wq_a, Wq_x, Wkv_a, Wkv_x, Wout_a, Wout_x,
      XN, WQT, WKVT, WOT, cosT, sinT);
  gemm_qkv_kernel<<<dim3(12, 32), dim3(256), 0, stream>>>(
      XN, WQT, WKVT, cosT, sinT, QB, KB, VT);
  attn_kernel<<<dim3(64, 16), dim3(256), 0, stream>>>(QB, KB, VT, AT);
  gemm_out_kernel<<<dim3(8, 32), dim3(256), 0, stream>>>(
      AT, WOT, bout_a, bout_x, out);
}

// Round 4
// 224.822 us; speedup vs baseline: 1.2052x; 1.0587x over previous
//
#include <hip/hip_runtime.h>
#include <hip/hip_bf16.h>
#include <stdint.h>
#include <math.h>

// ---------------------------------------------------------------------------
// JointAttention: dual-stream rmsnorm -> QKV proj -> RoPE -> joint attention
// over concat(a, x) (4096 tokens, 16 q-heads, 4 kv-heads tiled h%4) -> out proj.
// All matmuls in bf16 MFMA, fp32 accumulate.
//
// R12 = R9 attn geometry (q-tile 128, 4 waves = qsel x ksel, 36 MFMA/wave-
// tile, 2 blocks/CU) + TWO K-tiles per barrier interval:
//  - R11 showed occupancy is NOT the lever (2x waves, duplicated staging ->
//    97us). R9's limit is intra-wave QK->exp->PV serialization with both
//    SIMD waves phase-locked by the same per-tile barrier.
//  - R12: LDS pair-buffers (2 tiles per buffer, double-buffered, 72 KB);
//    one barrier per 2 tiles. Tile A and tile B chains are independent ->
//    compiler interleaves exp(A) VALU under QK/PV(B) MFMAs. Barriers halve.
//  - GEMMs: BM=64 tiles (64x128, acc[2][4]) -> gemm_qkv 768 blocks (3/CU),
//    gemm_out 512 blocks (2/CU); both were occupancy-starved (1-1.5/CU).
//    RoPE pairing (d with d+32) requires full 64-wide N per wave -> split M.
// ---------------------------------------------------------------------------

#define NSEQ 2048
#define NJ   4096
#define DIMM 1024
#define LPAD 72

typedef __attribute__((ext_vector_type(4))) float f32x4;
typedef __attribute__((ext_vector_type(8))) short bf16x8;
typedef __attribute__((ext_vector_type(4))) short bf16x4;

__device__ __forceinline__ unsigned short f2bf(float f) {
  union { float f; uint32_t u; } v; v.f = f;
  return (unsigned short)((v.u + 0x7FFFu + ((v.u >> 16) & 1u)) >> 16);
}

__device__ __forceinline__ uint32_t pack2bf(float a, float b) {
  __hip_bfloat162 h = __float22bfloat162_rn(float2{a, b});
  union { __hip_bfloat162 h; uint32_t u; } c; c.h = h;
  return c.u;
}

#if defined(__has_builtin)
#if __has_builtin(__builtin_amdgcn_exp2f)
#define FAST_EXP2(x) __builtin_amdgcn_exp2f(x)
#endif
#endif
#ifndef FAST_EXP2
#define FAST_EXP2(x) exp2f(x)
#endif

// async global->LDS, 16B per lane; LDS dest = wave-uniform base + lane*16
__device__ __forceinline__ void glds16(const void* g, void* l) {
  __builtin_amdgcn_global_load_lds(
      (const __attribute__((address_space(1))) unsigned int*)g,
      (__attribute__((address_space(3))) unsigned int*)l, 16, 0, 0);
}

// ---------------- fused prep: rope tables + weight cast + rmsnorm ----------
// flat grid, block-uniform branch:
//   [0,256)        rope tables (fp64 trig)
//   [256,6400)     weight cast+transpose f32[1024][N] -> bf16[N][1024]
//   [6400,10496)   rmsnorm + bf16 cast
__global__ __launch_bounds__(256) void prep_kernel(
    const float* __restrict__ xa, const float* __restrict__ xx,
    const float* __restrict__ ga, const float* __restrict__ gx,
    const float* __restrict__ wqa, const float* __restrict__ wqx,
    const float* __restrict__ wkva, const float* __restrict__ wkvx,
    const float* __restrict__ woa, const float* __restrict__ wox,
    unsigned short* __restrict__ XN, unsigned short* __restrict__ WQT,
    unsigned short* __restrict__ WKVT, unsigned short* __restrict__ WOT,
    float* __restrict__ cosT, float* __restrict__ sinT) {
  __shared__ float tile[32][33];
  __shared__ float red[4];
  int bid = blockIdx.x, t = threadIdx.x;
  if (bid < 256) {
    int idx = bid * 256 + t;                    // exactly NSEQ*32
    int pos = idx >> 5, i = idx & 31;
    double inv = pow(10000.0, -(double)i / 32.0);
    double ang = (double)(2 * pos) * inv;       // t = pos * (4096/2048)
    cosT[idx] = (float)cos(ang);
    sinT[idx] = (float)sin(ang);
  } else if (bid < 6400) {
    int b = bid - 256;
    int z = b >> 10, yx = b & 1023;
    int n0 = (yx >> 5) * 32, k0 = (yx & 31) * 32;
    int s = z & 1, ty = z >> 1;
    int N = (ty == 1) ? 512 : 1024;
    if (n0 >= N) return;                        // block-uniform
    const float* src = (z == 0) ? wqa : (z == 1) ? wqx : (z == 2) ? wkva
                     : (z == 3) ? wkvx : (z == 4) ? woa : wox;
    unsigned short* dst = (ty == 0) ? WQT + (size_t)s * 1024 * 1024
                        : (ty == 1) ? WKVT + (size_t)s * 512 * 1024
                                    : WOT + (size_t)s * 1024 * 1024;
    int r = t >> 3, c4 = (t & 7) * 4;
    f32x4 v = *(const f32x4*)(src + (size_t)(k0 + r) * N + n0 + c4);
    tile[r][c4 + 0] = v.x; tile[r][c4 + 1] = v.y;
    tile[r][c4 + 2] = v.z; tile[r][c4 + 3] = v.w;
    __syncthreads();
    int nn = t >> 3, kk = (t & 7) * 4;
    bf16x4 o;
    o.x = (short)f2bf(tile[kk + 0][nn]);
    o.y = (short)f2bf(tile[kk + 1][nn]);
    o.z = (short)f2bf(tile[kk + 2][nn]);
    o.w = (short)f2bf(tile[kk + 3][nn]);
    *(bf16x4*)(dst + (size_t)(n0 + nn) * 1024 + k0 + kk) = o;
  } else {
    int b = bid - 6400;
    int s = b >> 11, row = b & 2047;
    const float* src = (s == 0 ? xa : xx) + (size_t)row * DIMM;
    const float* g = (s == 0 ? ga : gx);
    f32x4 v = *(const f32x4*)(src + t * 4);
    float ss = v.x * v.x + v.y * v.y + v.z * v.z + v.w * v.w;
#pragma unroll
    for (int o = 32; o > 0; o >>= 1) ss += __shfl_xor(ss, o, 64);
    if ((t & 63) == 0) red[t >> 6] = ss;
    __syncthreads();
    float tot = red[0] + red[1] + red[2] + red[3];
    float rs = rsqrtf(tot * (1.0f / DIMM) + 1e-6f);
    f32x4 gv = *(const f32x4*)(g + t * 4);
    bf16x4 o;
    o.x = (short)f2bf(v.x * rs * gv.x);
    o.y = (short)f2bf(v.y * rs * gv.y);
    o.z = (short)f2bf(v.z * rs * gv.z);
    o.w = (short)f2bf(v.w * rs * gv.w);
    *(bf16x4*)(XN + ((size_t)s * NSEQ + row) * DIMM + t * 4) = o;
  }
}

// ---- shared 64x128x(K=1024) bf16 NT GEMM mainloop (BK=32, 4 waves) --------
// Wave = 32m x 64n: wm = (wid>>1)*32, wn = (wid&1)*64. acc[2][4].
// A-tile 64x32 (1 glds16), B-tile 128x32 (2 glds16).
__device__ __forceinline__ void gemm64_mainloop(
    const unsigned short* __restrict__ Ag, const unsigned short* __restrict__ Bg,
    unsigned short* As, unsigned short* Bs, f32x4 acc[2][4]) {
  int t = threadIdx.x;
  int lane = t & 63, wid = t >> 6;
  int wm = (wid >> 1) * 32, wn = (wid & 1) * 64;
  int l15 = lane & 15, quad = lane >> 4;
  int srow = t >> 2, sko = (t & 3) * 8;
  const unsigned short* ga = Ag + (size_t)srow * 1024 + sko;
  const unsigned short* gb = Bg + (size_t)srow * 1024 + sko;
  unsigned short* la = As + t * 8;
  unsigned short* lb = Bs + t * 8;
#pragma unroll
  for (int mi = 0; mi < 2; ++mi)
#pragma unroll
    for (int j = 0; j < 4; ++j) acc[mi][j] = (f32x4){0.f, 0.f, 0.f, 0.f};
  for (int kt = 0; kt < 32; ++kt) {
    int k0 = kt * 32;
    __syncthreads();                       // prev tile's frag reads done
    glds16(ga + k0, la);
    glds16(gb + k0, lb);
    glds16(gb + 64 * 1024 + k0, lb + 2048);
    __syncthreads();                       // drains vmcnt -> LDS visible
    bf16x8 af[2], bfr[4];
#pragma unroll
    for (int mi = 0; mi < 2; ++mi)
      af[mi] = *(const bf16x8*)(As + (wm + mi * 16 + l15) * 32 + quad * 8);
#pragma unroll
    for (int j = 0; j < 4; ++j)
      bfr[j] = *(const bf16x8*)(Bs + (wn + j * 16 + l15) * 32 + quad * 8);
#pragma unroll
    for (int mi = 0; mi < 2; ++mi)
#pragma unroll
      for (int j = 0; j < 4; ++j)
        acc[mi][j] = __builtin_amdgcn_mfma_f32_16x16x32_bf16(af[mi], bfr[j],
                                                             acc[mi][j], 0, 0, 0);
  }
}

// ------ QKV GEMM: A=[an;xn] (4096x1024), N=1536 (Q 1024 | K 256 | V 256) ---
// BM=64: grid 12 x 64 = 768 blocks (3/CU). Epilogue: RoPE on q/k; q also
// carries both softmax scales AND log2(e). Layouts QB[h][jr][d],
// KB[h][jr][d]; V written DIRECTLY transposed to VT[256][4096].
__global__ __launch_bounds__(256) void gemm_qkv_kernel(
    const unsigned short* __restrict__ XN, const unsigned short* __restrict__ WQT,
    const unsigned short* __restrict__ WKVT, const float* __restrict__ cosT,
    const float* __restrict__ sinT, unsigned short* __restrict__ QB,
    unsigned short* __restrict__ KB, unsigned short* __restrict__ VT) {
  __shared__ unsigned short As[64 * 32], Bs[128 * 32];
  int n0 = blockIdx.x * 128, m0 = blockIdx.y * 64;
  int s = (m0 >= 2048) ? 1 : 0;
  const unsigned short* Ag = XN + (size_t)m0 * 1024;
  const unsigned short* Bg = (n0 < 1024)
      ? WQT + (size_t)s * 1024 * 1024 + (size_t)n0 * 1024
      : WKVT + (size_t)s * 512 * 1024 + (size_t)(n0 - 1024) * 1024;
  f32x4 acc[2][4];
  gemm64_mainloop(Ag, Bg, As, Bs, acc);
  int t = threadIdx.x, lane = t & 63, wid = t >> 6;
  int wm = (wid >> 1) * 32, wn = (wid & 1) * 64;
  int l15 = lane & 15, quad = lane >> 4;
  int coln = n0 + wn;                     // 64-aligned -> head-uniform per wave
  if (coln < 1280) {
    bool isq = coln < 1024;
    float sc = isq ? (1.4426950408889634f / 64.0f) : 1.0f;  // 1/64 * log2(e)
    unsigned short* dstBase;
    if (isq) dstBase = QB + (size_t)(coln >> 6) * NJ * 64;
    else     dstBase = KB + (size_t)((coln - 1024) >> 6) * NJ * 64;
#pragma unroll
    for (int mi = 0; mi < 2; ++mi)
#pragma unroll
      for (int r = 0; r < 4; ++r) {
        int jr = m0 + wm + mi * 16 + quad * 4 + r;   // joint row (a:0..2047, x:2048..)
        int pos = jr & 2047;
#pragma unroll
        for (int jp = 0; jp < 2; ++jp) {             // d = jp*16+l15 pairs with d+32
          int i = jp * 16 + l15;
          float c = cosT[pos * 32 + i], sn = sinT[pos * 32 + i];
          float x1 = acc[mi][jp][r], x2 = acc[mi][jp + 2][r];
          dstBase[(size_t)jr * 64 + jp * 16 + l15]      = f2bf((x1 * c - x2 * sn) * sc);
          dstBase[(size_t)jr * 64 + 32 + jp * 16 + l15] = f2bf((x2 * c + x1 * sn) * sc);
        }
      }
  } else {
    // V: write straight to VT[d][jr] -- acc[mi][j][0..3] are 4 consecutive jr
    int cvb = coln - 1280;
#pragma unroll
    for (int mi = 0; mi < 2; ++mi)
#pragma unroll
      for (int j = 0; j < 4; ++j) {
        int d = cvb + j * 16 + l15;                  // 0..255 = hk*64 + dh
        int jr0 = m0 + wm + mi * 16 + quad * 4;
        union { bf16x4 v; uint32_t u[2]; } pv;
        pv.u[0] = pack2bf(acc[mi][j][0], acc[mi][j][1]);
        pv.u[1] = pack2bf(acc[mi][j][2], acc[mi][j][3]);
        *(bf16x4*)(VT + (size_t)d * NJ + jr0) = pv.v;
      }
  }
}

// ------------- flash attention: 128 q-rows x 1 head per block --------------
// R9 wave map: qsel = w>>1 picks 64 q rows (q0 + qsel*64 + mi*16 + l15,
// mi=0..3), ksel = w&1 picks the 32-key half. K staged PERMUTED (key k ->
// LDS row p(k)); kf reads use plain rows jb*16+l15 so row m of block jb
// holds key g(jb,m). Lane's exp'd S^T values = keys 32ksel+8quad+0..7 ->
// direct K=32 PV B-frag. lsum via ones-row MFMA.
// PAIRED TILES: LDS holds 2-tile pairs, double-buffered (72 KB); ONE
// barrier per 2 tiles; tile-A and tile-B compute chains are independent so
// exp(A) VALU overlaps QK/PV(B) MFMA. Reg prefetch one pair ahead.
// Key-split O^T/lsum partials combined once at the end via the LDS buffers.
__global__ __launch_bounds__(256, 2) void attn_kernel(
    const unsigned short* __restrict__ QB, const unsigned short* __restrict__ KB,
    const unsigned short* __restrict__ VT, unsigned short* __restrict__ AT) {
  __shared__ __align__(16) unsigned short Ks[2][2][64 * LPAD];  // [buf][tile]
  __shared__ __align__(16) unsigned short Vs[2][2][64 * LPAD];
  int h = blockIdx.y, qt = blockIdx.x;
  int hk = h & 3;                               // jnp.tile -> kv head = h % 4
  int t = threadIdx.x, lane = t & 63, w = t >> 6;
  int l15 = lane & 15, quad = lane >> 4;
  int qsel = w >> 1, ksel = w & 1;
  int q0 = qt * 128 + qsel * 64;                // wave's q rows: q0 + mi*16 + l15
  bf16x8 qf[4][2];
#pragma unroll
  for (int mi = 0; mi < 4; ++mi) {
    const unsigned short* qp = QB + ((size_t)h * NJ + q0 + mi * 16 + l15) * 64;
    qf[mi][0] = *(const bf16x8*)(qp + quad * 8);
    qf[mi][1] = *(const bf16x8*)(qp + 32 + quad * 8);
  }
  f32x4 oT[4][4];                               // O^T partial: [mi][db]
  f32x4 oL[4];                                  // ones-row accum (row0 = lsum)
#pragma unroll
  for (int mi = 0; mi < 4; ++mi) {
    oL[mi] = (f32x4){0.f, 0.f, 0.f, 0.f};
#pragma unroll
    for (int db = 0; db < 4; ++db) oT[mi][db] = (f32x4){0.f, 0.f, 0.f, 0.f};
  }
  // ones A-frag for K=32: A[m][k] = (m==0) ? 1.0 : 0
  bf16x8 vone;
  {
    short one = (l15 == 0) ? (short)0x3F80 : (short)0;
    vone = (bf16x8){one, one, one, one, one, one, one, one};
  }
  const unsigned short* Kg = KB + (size_t)hk * NJ * 64;   // [key][d]
  const unsigned short* Vg = VT + (size_t)hk * 64 * NJ;   // [d][key]
  int ky = t >> 3, dof = (t & 7) * 8;
  // write-side permutation: key k -> LDS row p(k); p(k+32) = p(k)+32
  int pky = (ky & 0x23) | ((ky & 0x18) >> 1) | ((ky & 0x04) << 2);
  const unsigned short* KgA = Kg + (size_t)ky * 64 + dof;        // +tile*4096
  const unsigned short* KgB = Kg + (size_t)(32 + ky) * 64 + dof;
  const unsigned short* VgA = Vg + (size_t)ky * NJ + dof;        // +tile*64
  const unsigned short* VgB = Vg + (size_t)(32 + ky) * NJ + dof;

#define STORE_TILE(KD, VD, K0, K1, V0, V1) do {                          \
    *(bf16x8*)((KD) + pky * LPAD + dof) = (K0);                          \
    *(bf16x8*)((KD) + (32 + pky) * LPAD + dof) = (K1);                   \
    *(bf16x8*)((VD) + ky * LPAD + dof) = (V0);                           \
    *(bf16x8*)((VD) + (32 + ky) * LPAD + dof) = (V1);                    \
  } while (0)

#define LOAD_TILE(K0, K1, V0, V1, TT) do {                               \
    size_t ko_ = (size_t)(TT) * 4096;                                    \
    int vo_ = (TT) * 64;                                                 \
    (K0) = *(const bf16x8*)(KgA + ko_);                                  \
    (K1) = *(const bf16x8*)(KgB + ko_);                                  \
    (V0) = *(const bf16x8*)(VgA + vo_);                                  \
    (V1) = *(const bf16x8*)(VgB + vo_);                                  \
  } while (0)

#define COMPUTE_TILE(KC, VC) do {                                        \
    const unsigned short* Kc_ = (KC);                                    \
    const unsigned short* Vc_ = (VC);                                    \
    f32x4 sx_[4][2];                                                     \
    _Pragma("unroll")                                                    \
    for (int jj = 0; jj < 2; ++jj) {                                     \
      int jb_ = 2 * ksel + jj;                                           \
      const unsigned short* kp_ = Kc_ + (jb_ * 16 + l15) * LPAD;         \
      bf16x8 kf0_ = *(const bf16x8*)(kp_ + quad * 8);                    \
      bf16x8 kf1_ = *(const bf16x8*)(kp_ + 32 + quad * 8);               \
      _Pragma("unroll")                                                  \
      for (int mi = 0; mi < 4; ++mi) {                                   \
        f32x4 z_ = (f32x4){0.f, 0.f, 0.f, 0.f};                          \
        z_ = __builtin_amdgcn_mfma_f32_16x16x32_bf16(kf0_, qf[mi][0], z_, 0, 0, 0); \
        z_ = __builtin_amdgcn_mfma_f32_16x16x32_bf16(kf1_, qf[mi][1], z_, 0, 0, 0); \
        sx_[mi][jj] = z_;                                                \
      }                                                                  \
    }                                                                    \
    bf16x8 pb_[4];                                                       \
    _Pragma("unroll")                                                    \
    for (int mi = 0; mi < 4; ++mi) {                                     \
      union { bf16x8 v; uint32_t u[4]; } pk_;                            \
      pk_.u[0] = pack2bf(FAST_EXP2(sx_[mi][0][0]), FAST_EXP2(sx_[mi][0][1])); \
      pk_.u[1] = pack2bf(FAST_EXP2(sx_[mi][0][2]), FAST_EXP2(sx_[mi][0][3])); \
      pk_.u[2] = pack2bf(FAST_EXP2(sx_[mi][1][0]), FAST_EXP2(sx_[mi][1][1])); \
      pk_.u[3] = pack2bf(FAST_EXP2(sx_[mi][1][2]), FAST_EXP2(sx_[mi][1][3])); \
      pb_[mi] = pk_.v;                                                   \
    }                                                                    \
    _Pragma("unroll")                                                    \
    for (int db = 0; db < 4; ++db) {                                     \
      bf16x8 va_ = *(const bf16x8*)(Vc_ + (db * 16 + l15) * LPAD + ksel * 32 + quad * 8); \
      _Pragma("unroll")                                                  \
      for (int mi = 0; mi < 4; ++mi)                                     \
        oT[mi][db] = __builtin_amdgcn_mfma_f32_16x16x32_bf16(va_, pb_[mi], oT[mi][db], 0, 0, 0); \
    }                                                                    \
    _Pragma("unroll")                                                    \
    for (int mi = 0; mi < 4; ++mi)                                       \
      oL[mi] = __builtin_amdgcn_mfma_f32_16x16x32_bf16(vone, pb_[mi], oL[mi], 0, 0, 0); \
  } while (0)

  // regs hold the NEXT pair (tiles 2p+2, 2p+3 during iter p)
  bf16x8 kA0, kA1, vA0, vA1, kB0, kB1, vB0, vB1;
  // preload pair 0 (tiles 0,1) -> buf0
  LOAD_TILE(kA0, kA1, vA0, vA1, 0);
  LOAD_TILE(kB0, kB1, vB0, vB1, 1);
  STORE_TILE(Ks[0][0], Vs[0][0], kA0, kA1, vA0, vA1);
  STORE_TILE(Ks[0][1], Vs[0][1], kB0, kB1, vB0, vB1);
  // prefetch pair 1 (tiles 2,3) -> regs
  LOAD_TILE(kA0, kA1, vA0, vA1, 2);
  LOAD_TILE(kB0, kB1, vB0, vB1, 3);
  __syncthreads();
  for (int pr = 0; pr < 32; ++pr) {
    int cur = pr & 1;
    // write pair pr+1 into other buffer (covered by pair pr-1 compute)
    STORE_TILE(Ks[cur ^ 1][0], Vs[cur ^ 1][0], kA0, kA1, vA0, vA1);
    STORE_TILE(Ks[cur ^ 1][1], Vs[cur ^ 1][1], kB0, kB1, vB0, vB1);
    // issue pair pr+2 loads (drained at end-of-iter barrier)
    int tA = (2 * pr + 4) & 63, tB = (2 * pr + 5) & 63;  // wrap: harmless
    LOAD_TILE(kA0, kA1, vA0, vA1, tA);
    LOAD_TILE(kB0, kB1, vB0, vB1, tB);
    // compute pair pr from buf cur: two independent chains -> overlap
    COMPUTE_TILE(Ks[cur][0], Vs[cur][0]);
    COMPUTE_TILE(Ks[cur][1], Vs[cur][1]);
    __syncthreads();                            // reads done; drains prefetch
  }
#undef STORE_TILE
#undef LOAD_TILE
#undef COMPUTE_TILE

  // ---- combine key-split partials across wave pairs (ksel 0 <- 1) ----
  // lsum: row0 lives on quad==0; quad-reduce first so every lane holds the
  // partial for q = l15 of each mi.
  float ls[4];
#pragma unroll
  for (int mi = 0; mi < 4; ++mi) {
    float s = oL[mi][0];
    s += __shfl_xor(s, 16, 64);
    s += __shfl_xor(s, 32, 64);
    ls[mi] = s;
  }
  // per-qsel scratch: qsel0 -> Ks area, qsel1 -> Vs area. oT with lane
  // stride 17 f32x4 (272 B); ls in the second buffer region.
  float* xb = (float*)(qsel == 0 ? &Ks[0][0][0] : &Vs[0][0][0]);
  float* xl = (float*)(qsel == 0 ? &Ks[1][0][0] : &Vs[1][0][0]);
  // main loop ended with __syncthreads(): all tile reads complete.
  if (ksel == 1) {
    f32x4* dst = (f32x4*)xb + (size_t)lane * 17;
#pragma unroll
    for (int mi = 0; mi < 4; ++mi)
#pragma unroll
      for (int db = 0; db < 4; ++db) dst[mi * 4 + db] = oT[mi][db];
    float* dl = xl + lane * 4;
#pragma unroll
    for (int mi = 0; mi < 4; ++mi) dl[mi] = ls[mi];
  }
  __syncthreads();
  if (ksel == 0) {
    const f32x4* src = (const f32x4*)xb + (size_t)lane * 17;
    const float* sl = xl + lane * 4;
#pragma unroll
    for (int mi = 0; mi < 4; ++mi) {
      float inv = 1.0f / (ls[mi] + sl[mi]);
      int qrow = q0 + mi * 16 + l15;
#pragma unroll
      for (int db = 0; db < 4; ++db) {
        f32x4 o = oT[mi][db] + src[mi * 4 + db];
        union { bf16x4 v; uint32_t u[2]; } ov;
        ov.u[0] = pack2bf(o[0] * inv, o[1] * inv);
        ov.u[1] = pack2bf(o[2] * inv, o[3] * inv);
        *(bf16x4*)(AT + (size_t)qrow * DIMM + h * 64 + db * 16 + quad * 4) = ov.v;
      }
    }
  }
}

// ---------------- output GEMM: AT (4096x1024) @ Wout^T + bias -> f32 -------
// BM=64: grid 8 x 64 = 512 blocks (2/CU).
__global__ __launch_bounds__(256) void gemm_out_kernel(
    const unsigned short* __restrict__ AT, const unsigned short* __restrict__ WOT,
    const float* __restrict__ ba, const float* __restrict__ bx,
    float* __restrict__ out) {
  __shared__ unsigned short As[64 * 32], Bs[128 * 32];
  int n0 = blockIdx.x * 128, m0 = blockIdx.y * 64;
  int s = (m0 >= 2048) ? 1 : 0;                 // 0 = a-stream rows, 1 = x
  const unsigned short* Ag = AT + (size_t)m0 * 1024;
  const unsigned short* Bg = WOT + (size_t)s * 1024 * 1024 + (size_t)n0 * 1024;
  f32x4 acc[2][4];
  gemm64_mainloop(Ag, Bg, As, Bs, acc);
  int t = threadIdx.x, lane = t & 63, wid = t >> 6;
  int wm = (wid >> 1) * 32, wn = (wid & 1) * 64;
  int l15 = lane & 15, quad = lane >> 4;
  const float* bias = s ? bx : ba;
  // d_out = [out_x (2048x1024) | out_a (2048x1024)]
  float* obase = s ? (out + (size_t)(m0 - 2048) * 1024)
                   : (out + (size_t)2048 * 1024 + (size_t)m0 * 1024);
#pragma unroll
  for (int mi = 0; mi < 2; ++mi)
#pragma unroll
    for (int r = 0; r < 4; ++r) {
      int row = wm + mi * 16 + quad * 4 + r;
#pragma unroll
      for (int j = 0; j < 4; ++j) {
        int col = n0 + wn + j * 16 + l15;
        obase[(size_t)row * 1024 + col] = acc[mi][j][r] + bias[col];
      }
    }
}

// ---------------------------------------------------------------------------
extern "C" void kernel_launch(void* const* d_in, const int* in_sizes, int n_in,
                              void* d_out, int out_size, void* d_ws, size_t ws_size,
                              hipStream_t stream) {
  const float* x      = (const float*)d_in[0];
  const float* a      = (const float*)d_in[1];
  const float* g_x    = (const float*)d_in[2];
  const float* g_a    = (const float*)d_in[3];
  const float* Wq_x   = (const float*)d_in[4];
  const float* Wkv_x  = (const float*)d_in[5];
  const float* Wq_a   = (const float*)d_in[6];
  const float* Wkv_a  = (const float*)d_in[7];
  const float* Wout_x = (const float*)d_in[8];
  const float* bout_x = (const float*)d_in[9];
  const float* Wout_a = (const float*)d_in[10];
  const float* bout_a = (const float*)d_in[11];
  float* out = (float*)d_out;

  // workspace (30.5 MB). AT aliases XN (dead after gemm_qkv).
  char* ws = (char*)d_ws;
  const size_t MB = 1024 * 1024;
  unsigned short* XN   = (unsigned short*)(ws);            // 8 MB
  unsigned short* WQT  = (unsigned short*)(ws + 8 * MB);   // 4 MB
  unsigned short* WKVT = (unsigned short*)(ws + 12 * MB);  // 2 MB
  unsigned short* WOT  = (unsigned short*)(ws + 14 * MB);  // 4 MB
  unsigned short* QB   = (unsigned short*)(ws + 18 * MB);  // 8 MB
  unsigned short* KB   = (unsigned short*)(ws + 26 * MB);  // 2 MB
  unsigned short* VT   = (unsigned short*)(ws + 28 * MB);  // 2 MB
  float* cosT          = (float*)(ws + 30 * MB);           // 256 KB
  float* sinT          = (float*)(ws + 30 * MB + 262144);  // 256 KB
  unsigned short* AT   = XN;                               // alias

  prep_kernel<<<dim3(10496), dim3(256), 0, stream>>>(
      a, x, g_a, g_x, Wq_a, Wq_x, Wkv_a, Wkv_x, Wout_a, Wout_x,
      XN, WQT, WKVT, WOT, cosT, sinT);
  gemm_qkv_kernel<<<dim3(12, 64), dim3(256), 0, stream>>>(
      XN, WQT, WKVT, cosT, sinT, QB, KB, VT);
  attn_kernel<<<dim3(32, 16), dim3(256), 0, stream>>>(QB, KB, VT, AT);
  gemm_out_kernel<<<dim3(8, 64), dim3(256), 0, stream>>>(
      AT, WOT, bout_a, bout_x, out);
}

// Round 5
// 217.190 us; speedup vs baseline: 1.2475x; 1.0351x over previous
//
#include <hip/hip_runtime.h>
#include <hip/hip_bf16.h>
#include <stdint.h>
#include <math.h>

// ---------------------------------------------------------------------------
// JointAttention: dual-stream rmsnorm -> QKV proj -> RoPE -> joint attention
// over concat(a, x) (4096 tokens, 16 q-heads, 4 kv-heads tiled h%4) -> out proj.
// All matmuls in bf16 MFMA, fp32 accumulate.
//
// R13: attn restructured for MFMA/VALU pipe overlap. R9-R12 all showed
// MfmaUtil+VALUBusy ~= 82% (pipes alternate, never overlap): identical
// barrier-locked wave streams serialize through QK(MFMA) -> exp(VALU) ->
// PV(MFMA) phases together. Fix:
//  - 1-tile-deep software pipeline: each half computes QK(t+1) INTERLEAVED
//    per-mi with exp(t) (independent work, 4 MFMA : ~14 VALU granularity),
//    then PV(t) (20 MFMA, setprio-wrapped). Mixed stream keeps both pipes
//    fed even with phase-locked waves.
//  - glds16 staging (removes reg-staging VALU+VGPR): LDS linear 64x64
//    tiles (4 slots, 64 KB); K row-permutation g(r) AND bank XOR-swizzle
//    (chunk ^= row&7) folded into the per-thread GLOBAL source address
//    (m173 both-sides pattern); reads XOR identically -> conflict-free.
//  - Loop unrolled x4 halves -> all slot offsets compile-time (ds imm).
//  - Wave map unchanged (qsel=w>>1: 64 q rows; ksel=w&1: 32-key half);
//    exp'd-S^T -> PV B-frag packing unchanged; lsum via ones-row MFMA.
// ---------------------------------------------------------------------------

#define NSEQ 2048
#define NJ   4096
#define DIMM 1024

typedef __attribute__((ext_vector_type(4))) float f32x4;
typedef __attribute__((ext_vector_type(8))) short bf16x8;
typedef __attribute__((ext_vector_type(4))) short bf16x4;

__device__ __forceinline__ unsigned short f2bf(float f) {
  union { float f; uint32_t u; } v; v.f = f;
  return (unsigned short)((v.u + 0x7FFFu + ((v.u >> 16) & 1u)) >> 16);
}

__device__ __forceinline__ uint32_t pack2bf(float a, float b) {
  __hip_bfloat162 h = __float22bfloat162_rn(float2{a, b});
  union { __hip_bfloat162 h; uint32_t u; } c; c.h = h;
  return c.u;
}

#if defined(__has_builtin)
#if __has_builtin(__builtin_amdgcn_exp2f)
#define FAST_EXP2(x) __builtin_amdgcn_exp2f(x)
#endif
#endif
#ifndef FAST_EXP2
#define FAST_EXP2(x) exp2f(x)
#endif

// async global->LDS, 16B per lane; LDS dest = wave-uniform base + lane*16
__device__ __forceinline__ void glds16(const void* g, void* l) {
  __builtin_amdgcn_global_load_lds(
      (const __attribute__((address_space(1))) unsigned int*)g,
      (__attribute__((address_space(3))) unsigned int*)l, 16, 0, 0);
}

// ---------------- fused prep: rope tables + weight cast + rmsnorm ----------
__global__ __launch_bounds__(256) void prep_kernel(
    const float* __restrict__ xa, const float* __restrict__ xx,
    const float* __restrict__ ga, const float* __restrict__ gx,
    const float* __restrict__ wqa, const float* __restrict__ wqx,
    const float* __restrict__ wkva, const float* __restrict__ wkvx,
    const float* __restrict__ woa, const float* __restrict__ wox,
    unsigned short* __restrict__ XN, unsigned short* __restrict__ WQT,
    unsigned short* __restrict__ WKVT, unsigned short* __restrict__ WOT,
    float* __restrict__ cosT, float* __restrict__ sinT) {
  __shared__ float tile[32][33];
  __shared__ float red[4];
  int bid = blockIdx.x, t = threadIdx.x;
  if (bid < 256) {
    int idx = bid * 256 + t;                    // exactly NSEQ*32
    int pos = idx >> 5, i = idx & 31;
    double inv = pow(10000.0, -(double)i / 32.0);
    double ang = (double)(2 * pos) * inv;       // t = pos * (4096/2048)
    cosT[idx] = (float)cos(ang);
    sinT[idx] = (float)sin(ang);
  } else if (bid < 6400) {
    int b = bid - 256;
    int z = b >> 10, yx = b & 1023;
    int n0 = (yx >> 5) * 32, k0 = (yx & 31) * 32;
    int s = z & 1, ty = z >> 1;
    int N = (ty == 1) ? 512 : 1024;
    if (n0 >= N) return;                        // block-uniform
    const float* src = (z == 0) ? wqa : (z == 1) ? wqx : (z == 2) ? wkva
                     : (z == 3) ? wkvx : (z == 4) ? woa : wox;
    unsigned short* dst = (ty == 0) ? WQT + (size_t)s * 1024 * 1024
                        : (ty == 1) ? WKVT + (size_t)s * 512 * 1024
                                    : WOT + (size_t)s * 1024 * 1024;
    int r = t >> 3, c4 = (t & 7) * 4;
    f32x4 v = *(const f32x4*)(src + (size_t)(k0 + r) * N + n0 + c4);
    tile[r][c4 + 0] = v.x; tile[r][c4 + 1] = v.y;
    tile[r][c4 + 2] = v.z; tile[r][c4 + 3] = v.w;
    __syncthreads();
    int nn = t >> 3, kk = (t & 7) * 4;
    bf16x4 o;
    o.x = (short)f2bf(tile[kk + 0][nn]);
    o.y = (short)f2bf(tile[kk + 1][nn]);
    o.z = (short)f2bf(tile[kk + 2][nn]);
    o.w = (short)f2bf(tile[kk + 3][nn]);
    *(bf16x4*)(dst + (size_t)(n0 + nn) * 1024 + k0 + kk) = o;
  } else {
    int b = bid - 6400;
    int s = b >> 11, row = b & 2047;
    const float* src = (s == 0 ? xa : xx) + (size_t)row * DIMM;
    const float* g = (s == 0 ? ga : gx);
    f32x4 v = *(const f32x4*)(src + t * 4);
    float ss = v.x * v.x + v.y * v.y + v.z * v.z + v.w * v.w;
#pragma unroll
    for (int o = 32; o > 0; o >>= 1) ss += __shfl_xor(ss, o, 64);
    if ((t & 63) == 0) red[t >> 6] = ss;
    __syncthreads();
    float tot = red[0] + red[1] + red[2] + red[3];
    float rs = rsqrtf(tot * (1.0f / DIMM) + 1e-6f);
    f32x4 gv = *(const f32x4*)(g + t * 4);
    bf16x4 o;
    o.x = (short)f2bf(v.x * rs * gv.x);
    o.y = (short)f2bf(v.y * rs * gv.y);
    o.z = (short)f2bf(v.z * rs * gv.z);
    o.w = (short)f2bf(v.w * rs * gv.w);
    *(bf16x4*)(XN + ((size_t)s * NSEQ + row) * DIMM + t * 4) = o;
  }
}

// ---- shared 64x128x(K=1024) bf16 NT GEMM mainloop (BK=32, 4 waves) --------
__device__ __forceinline__ void gemm64_mainloop(
    const unsigned short* __restrict__ Ag, const unsigned short* __restrict__ Bg,
    unsigned short* As, unsigned short* Bs, f32x4 acc[2][4]) {
  int t = threadIdx.x;
  int lane = t & 63, wid = t >> 6;
  int wm = (wid >> 1) * 32, wn = (wid & 1) * 64;
  int l15 = lane & 15, quad = lane >> 4;
  int srow = t >> 2, sko = (t & 3) * 8;
  const unsigned short* ga = Ag + (size_t)srow * 1024 + sko;
  const unsigned short* gb = Bg + (size_t)srow * 1024 + sko;
  unsigned short* la = As + t * 8;
  unsigned short* lb = Bs + t * 8;
#pragma unroll
  for (int mi = 0; mi < 2; ++mi)
#pragma unroll
    for (int j = 0; j < 4; ++j) acc[mi][j] = (f32x4){0.f, 0.f, 0.f, 0.f};
  for (int kt = 0; kt < 32; ++kt) {
    int k0 = kt * 32;
    __syncthreads();                       // prev tile's frag reads done
    glds16(ga + k0, la);
    glds16(gb + k0, lb);
    glds16(gb + 64 * 1024 + k0, lb + 2048);
    __syncthreads();                       // drains vmcnt -> LDS visible
    bf16x8 af[2], bfr[4];
#pragma unroll
    for (int mi = 0; mi < 2; ++mi)
      af[mi] = *(const bf16x8*)(As + (wm + mi * 16 + l15) * 32 + quad * 8);
#pragma unroll
    for (int j = 0; j < 4; ++j)
      bfr[j] = *(const bf16x8*)(Bs + (wn + j * 16 + l15) * 32 + quad * 8);
#pragma unroll
    for (int mi = 0; mi < 2; ++mi)
#pragma unroll
      for (int j = 0; j < 4; ++j)
        acc[mi][j] = __builtin_amdgcn_mfma_f32_16x16x32_bf16(af[mi], bfr[j],
                                                             acc[mi][j], 0, 0, 0);
  }
}

// ------ QKV GEMM: A=[an;xn] (4096x1024), N=1536 (Q 1024 | K 256 | V 256) ---
__global__ __launch_bounds__(256) void gemm_qkv_kernel(
    const unsigned short* __restrict__ XN, const unsigned short* __restrict__ WQT,
    const unsigned short* __restrict__ WKVT, const float* __restrict__ cosT,
    const float* __restrict__ sinT, unsigned short* __restrict__ QB,
    unsigned short* __restrict__ KB, unsigned short* __restrict__ VT) {
  __shared__ unsigned short As[64 * 32], Bs[128 * 32];
  int n0 = blockIdx.x * 128, m0 = blockIdx.y * 64;
  int s = (m0 >= 2048) ? 1 : 0;
  const unsigned short* Ag = XN + (size_t)m0 * 1024;
  const unsigned short* Bg = (n0 < 1024)
      ? WQT + (size_t)s * 1024 * 1024 + (size_t)n0 * 1024
      : WKVT + (size_t)s * 512 * 1024 + (size_t)(n0 - 1024) * 1024;
  f32x4 acc[2][4];
  gemm64_mainloop(Ag, Bg, As, Bs, acc);
  int t = threadIdx.x, lane = t & 63, wid = t >> 6;
  int wm = (wid >> 1) * 32, wn = (wid & 1) * 64;
  int l15 = lane & 15, quad = lane >> 4;
  int coln = n0 + wn;                     // 64-aligned -> head-uniform per wave
  if (coln < 1280) {
    bool isq = coln < 1024;
    float sc = isq ? (1.4426950408889634f / 64.0f) : 1.0f;  // 1/64 * log2(e)
    unsigned short* dstBase;
    if (isq) dstBase = QB + (size_t)(coln >> 6) * NJ * 64;
    else     dstBase = KB + (size_t)((coln - 1024) >> 6) * NJ * 64;
#pragma unroll
    for (int mi = 0; mi < 2; ++mi)
#pragma unroll
      for (int r = 0; r < 4; ++r) {
        int jr = m0 + wm + mi * 16 + quad * 4 + r;   // joint row (a:0..2047, x:2048..)
        int pos = jr & 2047;
#pragma unroll
        for (int jp = 0; jp < 2; ++jp) {             // d = jp*16+l15 pairs with d+32
          int i = jp * 16 + l15;
          float c = cosT[pos * 32 + i], sn = sinT[pos * 32 + i];
          float x1 = acc[mi][jp][r], x2 = acc[mi][jp + 2][r];
          dstBase[(size_t)jr * 64 + jp * 16 + l15]      = f2bf((x1 * c - x2 * sn) * sc);
          dstBase[(size_t)jr * 64 + 32 + jp * 16 + l15] = f2bf((x2 * c + x1 * sn) * sc);
        }
      }
  } else {
    // V: write straight to VT[d][jr] -- acc[mi][j][0..3] are 4 consecutive jr
    int cvb = coln - 1280;
#pragma unroll
    for (int mi = 0; mi < 2; ++mi)
#pragma unroll
      for (int j = 0; j < 4; ++j) {
        int d = cvb + j * 16 + l15;                  // 0..255 = hk*64 + dh
        int jr0 = m0 + wm + mi * 16 + quad * 4;
        union { bf16x4 v; uint32_t u[2]; } pv;
        pv.u[0] = pack2bf(acc[mi][j][0], acc[mi][j][1]);
        pv.u[1] = pack2bf(acc[mi][j][2], acc[mi][j][3]);
        *(bf16x4*)(VT + (size_t)d * NJ + jr0) = pv.v;
      }
  }
}

// ------------- flash attention: 128 q-rows x 1 head per block --------------
// 4 single-tile LDS slots (64x64 bf16, linear, XOR-swizzled content), slot =
// tile&3, staged via glds16 with pre-permuted/pre-swizzled global source:
//   LDS K row r <- key g(r) = 32(r>>5) + 8((r>>2)&3) + 4((r>>4)&1) + (r&3),
//   16B-chunk c of row r <- original chunk c ^ (r&7)  (both K and V).
// Reads XOR identically. Software pipeline per half:
//   stage(t+2); { QK(t+1, mi) 4 MFMA ; exp(t, mi) }x4 ; PV(t) 20 MFMA; bar.
// Unrolled x4 halves so slot offsets are compile-time ds immediates.
__global__ __launch_bounds__(256, 2) void attn_kernel(
    const unsigned short* __restrict__ QB, const unsigned short* __restrict__ KB,
    const unsigned short* __restrict__ VT, unsigned short* __restrict__ AT) {
  __shared__ __align__(16) unsigned short Ks[4][4096];   // 4 slots x 64x64
  __shared__ __align__(16) unsigned short Vs[4][4096];
  int h = blockIdx.y, qt = blockIdx.x;
  int hk = h & 3;                               // jnp.tile -> kv head = h % 4
  int t = threadIdx.x, lane = t & 63, w = t >> 6;
  int l15 = lane & 15, quad = lane >> 4;
  int qsel = w >> 1, ksel = w & 1;
  int q0 = qt * 128 + qsel * 64;                // wave's q rows: q0 + mi*16 + l15
  bf16x8 qf[4][2];
#pragma unroll
  for (int mi = 0; mi < 4; ++mi) {
    const unsigned short* qp = QB + ((size_t)h * NJ + q0 + mi * 16 + l15) * 64;
    qf[mi][0] = *(const bf16x8*)(qp + quad * 8);
    qf[mi][1] = *(const bf16x8*)(qp + 32 + quad * 8);
  }
  f32x4 oT[4][4];                               // O^T partial: [mi][db]
  f32x4 oL[4];                                  // ones-row accum (row0 = lsum)
#pragma unroll
  for (int mi = 0; mi < 4; ++mi) {
    oL[mi] = (f32x4){0.f, 0.f, 0.f, 0.f};
#pragma unroll
    for (int db = 0; db < 4; ++db) oT[mi][db] = (f32x4){0.f, 0.f, 0.f, 0.f};
  }
  bf16x8 vone;                                  // ones A-frag (row 0 only)
  {
    short one = (l15 == 0) ? (short)0x3F80 : (short)0;
    vone = (bf16x8){one, one, one, one, one, one, one, one};
  }
  const unsigned short* Kg = KB + (size_t)hk * NJ * 64;   // [key][d]
  const unsigned short* Vg = VT + (size_t)hk * 64 * NJ;   // [d][key]
  // ---- glds16 source addresses (per thread, loop-invariant) ----
  int r1 = t >> 3, cx = t & 7;
  int e1 = r1 & 7;
  int c1 = cx ^ e1;                             // swizzled 16B chunk
  int gk1 = 32 * (r1 >> 5) + 8 * ((r1 >> 2) & 3) + 4 * ((r1 >> 4) & 1) + (r1 & 3);
  int r2 = r1 + 32;
  int gk2 = 32 * (r2 >> 5) + 8 * ((r2 >> 2) & 3) + 4 * ((r2 >> 4) & 1) + (r2 & 3);
  const unsigned short* sK1 = Kg + (size_t)gk1 * 64 + c1 * 8;   // +tile*4096
  const unsigned short* sK2 = Kg + (size_t)gk2 * 64 + c1 * 8;
  const unsigned short* sV1 = Vg + (size_t)r1 * NJ + c1 * 8;    // +tile*64
  const unsigned short* sV2 = Vg + (size_t)r2 * NJ + c1 * 8;
  // ---- ds_read addresses (per lane, loop-invariant; + slot*4096 shorts) ----
  int e = l15 & 7;
  int co0 = (quad ^ e) * 8;                     // K lo chunk (d 0..31 quarter)
  int co1 = ((4 + quad) ^ e) * 8;               // K hi chunk
  int cov = (((ksel << 2) | quad) ^ e) * 8;     // V chunk (key half ksel)
  const unsigned short* kf0p = &Ks[0][(2 * ksel * 16 + l15) * 64] + co0;
  const unsigned short* kf0q = &Ks[0][(2 * ksel * 16 + l15) * 64] + co1;
  const unsigned short* kf1p = kf0p + 16 * 64;
  const unsigned short* kf1q = kf0q + 16 * 64;
  const unsigned short* vap0 = &Vs[0][(0 * 16 + l15) * 64] + cov;
  const unsigned short* vap1 = &Vs[0][(1 * 16 + l15) * 64] + cov;
  const unsigned short* vap2 = &Vs[0][(2 * 16 + l15) * 64] + cov;
  const unsigned short* vap3 = &Vs[0][(3 * 16 + l15) * 64] + cov;

  f32x4 sxA[4][2], sxB[4][2];
  bf16x8 pb[4];

#define STAGE(S, T) do {                                                   \
    size_t ko_ = (size_t)(T) * 4096;                                       \
    int vo_ = (T) * 64;                                                    \
    glds16(sK1 + ko_, &Ks[S][0] + t * 8);                                  \
    glds16(sK2 + ko_, &Ks[S][2048] + t * 8);                               \
    glds16(sV1 + vo_, &Vs[S][0] + t * 8);                                  \
    glds16(sV2 + vo_, &Vs[S][2048] + t * 8);                               \
  } while (0)

  // QK only (prologue): tile in slot S -> SX
#define QK4(S, SX) do {                                                    \
    bf16x8 k00 = *(const bf16x8*)(kf0p + (S) * 4096);                      \
    bf16x8 k01 = *(const bf16x8*)(kf0q + (S) * 4096);                      \
    bf16x8 k10 = *(const bf16x8*)(kf1p + (S) * 4096);                      \
    bf16x8 k11 = *(const bf16x8*)(kf1q + (S) * 4096);                      \
    _Pragma("unroll")                                                      \
    for (int mi = 0; mi < 4; ++mi) {                                       \
      f32x4 z0 = (f32x4){0.f, 0.f, 0.f, 0.f};                              \
      z0 = __builtin_amdgcn_mfma_f32_16x16x32_bf16(k00, qf[mi][0], z0, 0, 0, 0); \
      z0 = __builtin_amdgcn_mfma_f32_16x16x32_bf16(k01, qf[mi][1], z0, 0, 0, 0); \
      (SX)[mi][0] = z0;                                                    \
      f32x4 z1 = (f32x4){0.f, 0.f, 0.f, 0.f};                              \
      z1 = __builtin_amdgcn_mfma_f32_16x16x32_bf16(k10, qf[mi][0], z1, 0, 0, 0); \
      z1 = __builtin_amdgcn_mfma_f32_16x16x32_bf16(k11, qf[mi][1], z1, 0, 0, 0); \
      (SX)[mi][1] = z1;                                                    \
    }                                                                      \
  } while (0)

  // interleaved: QK(next tile, slot SQ) -> SXN while exp(SXP) -> pb
#define PHASE_A(SQ, SXN, SXP) do {                                         \
    bf16x8 k00 = *(const bf16x8*)(kf0p + (SQ) * 4096);                     \
    bf16x8 k01 = *(const bf16x8*)(kf0q + (SQ) * 4096);                     \
    bf16x8 k10 = *(const bf16x8*)(kf1p + (SQ) * 4096);                     \
    bf16x8 k11 = *(const bf16x8*)(kf1q + (SQ) * 4096);                     \
    _Pragma("unroll")                                                      \
    for (int mi = 0; mi < 4; ++mi) {                                       \
      f32x4 z0 = (f32x4){0.f, 0.f, 0.f, 0.f};                              \
      z0 = __builtin_amdgcn_mfma_f32_16x16x32_bf16(k00, qf[mi][0], z0, 0, 0, 0); \
      z0 = __builtin_amdgcn_mfma_f32_16x16x32_bf16(k01, qf[mi][1], z0, 0, 0, 0); \
      (SXN)[mi][0] = z0;                                                   \
      f32x4 z1 = (f32x4){0.f, 0.f, 0.f, 0.f};                              \
      z1 = __builtin_amdgcn_mfma_f32_16x16x32_bf16(k10, qf[mi][0], z1, 0, 0, 0); \
      z1 = __builtin_amdgcn_mfma_f32_16x16x32_bf16(k11, qf[mi][1], z1, 0, 0, 0); \
      (SXN)[mi][1] = z1;                                                   \
      union { bf16x8 v; uint32_t u[4]; } pk_;                              \
      pk_.u[0] = pack2bf(FAST_EXP2((SXP)[mi][0][0]), FAST_EXP2((SXP)[mi][0][1])); \
      pk_.u[1] = pack2bf(FAST_EXP2((SXP)[mi][0][2]), FAST_EXP2((SXP)[mi][0][3])); \
      pk_.u[2] = pack2bf(FAST_EXP2((SXP)[mi][1][0]), FAST_EXP2((SXP)[mi][1][1])); \
      pk_.u[3] = pack2bf(FAST_EXP2((SXP)[mi][1][2]), FAST_EXP2((SXP)[mi][1][3])); \
      pb[mi] = pk_.v;                                                      \
    }                                                                      \
  } while (0)

#define PHASE_B(SP) do {                                                   \
    __builtin_amdgcn_s_setprio(1);                                         \
    {                                                                      \
      bf16x8 va0 = *(const bf16x8*)(vap0 + (SP) * 4096);                   \
      bf16x8 va1 = *(const bf16x8*)(vap1 + (SP) * 4096);                   \
      bf16x8 va2 = *(const bf16x8*)(vap2 + (SP) * 4096);                   \
      bf16x8 va3 = *(const bf16x8*)(vap3 + (SP) * 4096);                   \
      _Pragma("unroll")                                                    \
      for (int mi = 0; mi < 4; ++mi) {                                     \
        oT[mi][0] = __builtin_amdgcn_mfma_f32_16x16x32_bf16(va0, pb[mi], oT[mi][0], 0, 0, 0); \
        oT[mi][1] = __builtin_amdgcn_mfma_f32_16x16x32_bf16(va1, pb[mi], oT[mi][1], 0, 0, 0); \
        oT[mi][2] = __builtin_amdgcn_mfma_f32_16x16x32_bf16(va2, pb[mi], oT[mi][2], 0, 0, 0); \
        oT[mi][3] = __builtin_amdgcn_mfma_f32_16x16x32_bf16(va3, pb[mi], oT[mi][3], 0, 0, 0); \
        oL[mi] = __builtin_amdgcn_mfma_f32_16x16x32_bf16(vone, pb[mi], oL[mi], 0, 0, 0); \
      }                                                                    \
    }                                                                      \
    __builtin_amdgcn_s_setprio(0);                                         \
  } while (0)

  // prologue: stage tiles 0,1; QK(0) -> sxA
  STAGE(0, 0);
  STAGE(1, 1);
  __syncthreads();                              // drains vmcnt -> visible
  QK4(0, sxA);
  for (int P = 0; P < 16; ++P) {
    int tb = 4 * P;
    // half 1: PV(tb)@s0, QK(tb+1)@s1 || exp(tb), stage(tb+2)->s2
    STAGE(2, (tb + 2) & 63);
    PHASE_A(1, sxB, sxA);
    PHASE_B(0);
    __syncthreads();
    // half 2: PV(tb+1)@s1, QK(tb+2)@s2 || exp(tb+1), stage(tb+3)->s3
    STAGE(3, (tb + 3) & 63);
    PHASE_A(2, sxA, sxB);
    PHASE_B(1);
    __syncthreads();
    // half 3: PV(tb+2)@s2, QK(tb+3)@s3 || exp(tb+2), stage(tb+4)->s0
    STAGE(0, (tb + 4) & 63);
    PHASE_A(3, sxB, sxA);
    PHASE_B(2);
    __syncthreads();
    // half 4: PV(tb+3)@s3, QK(tb+4)@s0 || exp(tb+3), stage(tb+5)->s1
    STAGE(1, (tb + 5) & 63);
    PHASE_A(0, sxA, sxB);
    PHASE_B(3);
    __syncthreads();
  }
#undef STAGE
#undef QK4
#undef PHASE_A
#undef PHASE_B

  // ---- combine key-split partials across wave pairs (ksel 0 <- 1) ----
  float ls[4];
#pragma unroll
  for (int mi = 0; mi < 4; ++mi) {
    float s = oL[mi][0];
    s += __shfl_xor(s, 16, 64);
    s += __shfl_xor(s, 32, 64);
    ls[mi] = s;
  }
  // per-qsel scratch: qsel0 -> Ks region (32 KB), qsel1 -> Vs region.
  // oT at lane stride 17 f32x4 (272 B); ls after (offset 64*68 floats).
  float* xb = (qsel == 0) ? (float*)&Ks[0][0] : (float*)&Vs[0][0];
  float* xl = xb + 64 * 68;
  // main loop ended with __syncthreads(): all tile reads complete.
  if (ksel == 1) {
    f32x4* dst = (f32x4*)xb + (size_t)lane * 17;
#pragma unroll
    for (int mi = 0; mi < 4; ++mi)
#pragma unroll
      for (int db = 0; db < 4; ++db) dst[mi * 4 + db] = oT[mi][db];
    float* dl = xl + lane * 4;
#pragma unroll
    for (int mi = 0; mi < 4; ++mi) dl[mi] = ls[mi];
  }
  __syncthreads();
  if (ksel == 0) {
    const f32x4* src = (const f32x4*)xb + (size_t)lane * 17;
    const float* sl = xl + lane * 4;
#pragma unroll
    for (int mi = 0; mi < 4; ++mi) {
      float inv = 1.0f / (ls[mi] + sl[mi]);
      int qrow = q0 + mi * 16 + l15;
#pragma unroll
      for (int db = 0; db < 4; ++db) {
        f32x4 o = oT[mi][db] + src[mi * 4 + db];
        union { bf16x4 v; uint32_t u[2]; } ov;
        ov.u[0] = pack2bf(o[0] * inv, o[1] * inv);
        ov.u[1] = pack2bf(o[2] * inv, o[3] * inv);
        *(bf16x4*)(AT + (size_t)qrow * DIMM + h * 64 + db * 16 + quad * 4) = ov.v;
      }
    }
  }
}

// ---------------- output GEMM: AT (4096x1024) @ Wout^T + bias -> f32 -------
__global__ __launch_bounds__(256) void gemm_out_kernel(
    const unsigned short* __restrict__ AT, const unsigned short* __restrict__ WOT,
    const float* __restrict__ ba, const float* __restrict__ bx,
    float* __restrict__ out) {
  __shared__ unsigned short As[64 * 32], Bs[128 * 32];
  int n0 = blockIdx.x * 128, m0 = blockIdx.y * 64;
  int s = (m0 >= 2048) ? 1 : 0;                 // 0 = a-stream rows, 1 = x
  const unsigned short* Ag = AT + (size_t)m0 * 1024;
  const unsigned short* Bg = WOT + (size_t)s * 1024 * 1024 + (size_t)n0 * 1024;
  f32x4 acc[2][4];
  gemm64_mainloop(Ag, Bg, As, Bs, acc);
  int t = threadIdx.x, lane = t & 63, wid = t >> 6;
  int wm = (wid >> 1) * 32, wn = (wid & 1) * 64;
  int l15 = lane & 15, quad = lane >> 4;
  const float* bias = s ? bx : ba;
  // d_out = [out_x (2048x1024) | out_a (2048x1024)]
  float* obase = s ? (out + (size_t)(m0 - 2048) * 1024)
                   : (out + (size_t)2048 * 1024 + (size_t)m0 * 1024);
#pragma unroll
  for (int mi = 0; mi < 2; ++mi)
#pragma unroll
    for (int r = 0; r < 4; ++r) {
      int row = wm + mi * 16 + quad * 4 + r;
#pragma unroll
      for (int j = 0; j < 4; ++j) {
        int col = n0 + wn + j * 16 + l15;
        obase[(size_t)row * 1024 + col] = acc[mi][j][r] + bias[col];
      }
    }
}

// ---------------------------------------------------------------------------
extern "C" void kernel_launch(void* const* d_in, const int* in_sizes, int n_in,
                              void* d_out, int out_size, void* d_ws, size_t ws_size,
                              hipStream_t stream) {
  const float* x      = (const float*)d_in[0];
  const float* a      = (const float*)d_in[1];
  const float* g_x    = (const float*)d_in[2];
  const float* g_a    = (const float*)d_in[3];
  const float* Wq_x   = (const float*)d_in[4];
  const float* Wkv_x  = (const float*)d_in[5];
  const float* Wq_a   = (const float*)d_in[6];
  const float* Wkv_a  = (const float*)d_in[7];
  const float* Wout_x = (const float*)d_in[8];
  const float* bout_x = (const float*)d_in[9];
  const float* Wout_a = (const float*)d_in[10];
  const float* bout_a = (const float*)d_in[11];
  float* out = (float*)d_out;

  // workspace (30.5 MB). AT aliases XN (dead after gemm_qkv).
  char* ws = (char*)d_ws;
  const size_t MB = 1024 * 1024;
  unsigned short* XN   = (unsigned short*)(ws);            // 8 MB
  unsigned short* WQT  = (unsigned short*)(ws + 8 * MB);   // 4 MB
  unsigned short* WKVT = (unsigned short*)(ws + 12 * MB);  // 2 MB
  unsigned short* WOT  = (unsigned short*)(ws + 14 * MB);  // 4 MB
  unsigned short* QB   = (unsigned short*)(ws + 18 * MB);  // 8 MB
  unsigned short* KB   = (unsigned short*)(ws + 26 * MB);  // 2 MB
  unsigned short* VT   = (unsigned short*)(ws + 28 * MB);  // 2 MB
  float* cosT          = (float*)(ws + 30 * MB);           // 256 KB
  float* sinT          = (float*)(ws + 30 * MB + 262144);  // 256 KB
  unsigned short* AT   = XN;                               // alias

  prep_kernel<<<dim3(10496), dim3(256), 0, stream>>>(
      a, x, g_a, g_x, Wq_a, Wq_x, Wkv_a, Wkv_x, Wout_a, Wout_x,
      XN, WQT, WKVT, WOT, cosT, sinT);
  gemm_qkv_kernel<<<dim3(12, 64), dim3(256), 0, stream>>>(
      XN, WQT, WKVT, cosT, sinT, QB, KB, VT);
  attn_kernel<<<dim3(32, 16), dim3(256), 0, stream>>>(QB, KB, VT, AT);
  gemm_out_kernel<<<dim3(8, 64), dim3(256), 0, stream>>>(
      AT, WOT, bout_a, bout_x, out);
}